// Round 7
// baseline (1370.098 us; speedup 1.0000x reference)
//
#include <hip/hip_runtime.h>
#include <hip/hip_bf16.h>

#define M_TOK   25088
#define C_DIM   256
#define NH      8
#define HID_DIM 1024
#define PSTR    40          // pbuf row stride in shorts (80B: b128-aligned, conflict-free)

typedef __attribute__((ext_vector_type(8))) short short8;
typedef __attribute__((ext_vector_type(4))) short short4v;
typedef __attribute__((ext_vector_type(4))) float f32x4;
typedef __attribute__((ext_vector_type(2))) unsigned uint2v;

__device__ __forceinline__ short f2bf(float f) {
    return __builtin_bit_cast(short, __float2bfloat16(f));
}
__device__ __forceinline__ float bf2f(short s) {
    return __bfloat162float(__builtin_bit_cast(__hip_bfloat16, s));
}

__device__ __forceinline__ int map_t(int branch, int w, int n) {
    if (branch == 0) {
        return w * 784 + n;
    } else if (branch == 1) {
        int b = w >> 4, wc = w & 15;
        int h2 = n / 7, s = n - h2 * 7;
        return b * 12544 + h2 * 112 + wc * 7 + s;
    } else {
        int b = w >> 6, wi = w & 63;
        int wh = wi >> 3, ww = wi & 7;
        int i = n / 14, j = n - i * 14;
        return b * 12544 + (wh * 14 + i) * 112 + ww * 14 + j;
    }
}

template<int BR>
__device__ __forceinline__ void tok2win(int t, int& w, int& n) {
    if constexpr (BR == 0) {
        w = t / 784; n = t - w * 784;
    } else if constexpr (BR == 1) {
        int b = t / 12544, r = t - b * 12544;
        int h2 = r / 112, cc = r - h2 * 112;
        int wc = cc / 7, s = cc - wc * 7;
        w = b * 16 + wc; n = h2 * 7 + s;
    } else {
        int b = t / 12544, r = t - b * 12544;
        int ii = r / 112, jj = r - ii * 112;
        int wh = ii / 14, i = ii - wh * 14;
        int ww = jj / 14, j = jj - ww * 14;
        w = b * 64 + wh * 8 + ww; n = i * 14 + j;
    }
}

__global__ void detect_kernel(const unsigned* __restrict__ g1, int* flag) {
    if (threadIdx.x == 0) *flag = (g1[0] == 0x3F800000u) ? 1 : 0;
}

__global__ void convert_kernel(const void* __restrict__ src,
                               short* __restrict__ dst, int n,
                               const int* __restrict__ flag) {
    int i = blockIdx.x * 256 + threadIdx.x;
    if (i >= n) return;
    if (*flag) dst[i] = f2bf(((const float*)src)[i]);
    else       dst[i] = ((const short*)src)[i];
}

// Precompute attn3 bias matrix: bmat[h][n1][n2] (bf16), n1,n2 in [0,196)
__global__ void biasmat_kernel(const short* __restrict__ rpb,
                               short* __restrict__ bmat) {
    int idx = blockIdx.x * 256 + threadIdx.x;
    if (idx >= 8 * 196 * 196) return;
    int h = idx / 38416, rest = idx - h * 38416;
    int n1 = rest / 196, n2 = rest - n1 * 196;
    int i1 = n1 / 14, j1 = n1 - i1 * 14;
    int i2 = n2 / 14, j2 = n2 - i2 * 14;
    bmat[idx] = rpb[((i1 - i2 + 13) * 27 + (j1 - j2 + 13)) * 8 + h];
}

__global__ __launch_bounds__(256) void ln_kernel(
    const void* __restrict__ x, const short* __restrict__ g,
    const short* __restrict__ b, short* __restrict__ out,
    const int* __restrict__ flag)
{
    int t = blockIdx.x * 4 + (threadIdx.x >> 6);
    int lane = threadIdx.x & 63;
    size_t base = (size_t)t * C_DIM + lane * 4;
    float v[4];
    if (*flag) {
        f32x4 hv = *(const f32x4*)((const float*)x + base);
        #pragma unroll
        for (int j = 0; j < 4; ++j) v[j] = hv[j];
    } else {
        short4v hv = *(const short4v*)((const short*)x + base);
        #pragma unroll
        for (int j = 0; j < 4; ++j) v[j] = bf2f(hv[j]);
    }
    float s = v[0] + v[1] + v[2] + v[3];
    float ss = v[0]*v[0] + v[1]*v[1] + v[2]*v[2] + v[3]*v[3];
    for (int off = 32; off; off >>= 1) {
        s  += __shfl_xor(s, off);
        ss += __shfl_xor(ss, off);
    }
    float mean = s * (1.f / 256.f);
    float var  = fmaxf(ss * (1.f / 256.f) - mean * mean, 0.f);
    float rstd = rsqrtf(var + 1e-5f);
    short4v hg = *(const short4v*)(g + lane * 4);
    short4v hb = *(const short4v*)(b + lane * 4);
    short4v o;
    #pragma unroll
    for (int j = 0; j < 4; ++j)
        o[j] = f2bf((v[j] - mean) * rstd * bf2f(hg[j]) + bf2f(hb[j]));
    *(short4v*)(out + base) = o;
}

// Transpose + optional column prescale (src cols < scaleCols get * smul)
__global__ void transpose_kernel(const void* __restrict__ src,
                                 short* __restrict__ dst, int R, int Cc,
                                 const int* __restrict__ flag,
                                 int scaleCols, float smul)
{
    __shared__ short tile[32][33];
    int c0 = blockIdx.x * 32, r0 = blockIdx.y * 32;
    int tx = threadIdx.x, ty = threadIdx.y;
    int fp32 = *flag;
    #pragma unroll
    for (int i = 0; i < 32; i += 8) {
        int r = r0 + ty + i, c = c0 + tx;
        if (r < R && c < Cc) {
            size_t idx = (size_t)r * Cc + c;
            float v = fp32 ? ((const float*)src)[idx] : bf2f(((const short*)src)[idx]);
            if (c < scaleCols) v *= smul;
            tile[ty + i][tx] = f2bf(v);
        }
    }
    __syncthreads();
    #pragma unroll
    for (int i = 0; i < 32; i += 8) {
        int r = c0 + ty + i, c = r0 + tx;
        if (r < Cc && c < R) dst[(size_t)r * R + c] = tile[tx][ty + i];
    }
}

// Out row index = m0 + local m. oflag: null->bf16 out; else dtype per *oflag.
__global__ __launch_bounds__(256) void gemm_kernel(
    const short* __restrict__ A, const short* __restrict__ Bt,
    void* __restrict__ Out, int m0, int Nn, int Kk,
    const short* __restrict__ bias, int act, const short* __restrict__ res,
    const int* __restrict__ oflag)
{
    int lane = threadIdx.x & 63;
    int wid  = threadIdx.x >> 6;
    int waveM = wid >> 1, waveN = wid & 1;
    int mb = blockIdx.y * 64 + waveM * 32;
    int nb = blockIdx.x * 64 + waveN * 32;
    int r16 = lane & 15, q4 = lane >> 4;

    f32x4 acc[2][2];
    #pragma unroll
    for (int i = 0; i < 2; ++i)
        #pragma unroll
        for (int j = 0; j < 2; ++j)
            acc[i][j] = (f32x4){0.f, 0.f, 0.f, 0.f};

    const short* Ar0 = A  + (size_t)(mb + r16) * Kk + q4 * 8;
    const short* Ar1 = A  + (size_t)(mb + 16 + r16) * Kk + q4 * 8;
    const short* Br0 = Bt + (size_t)(nb + r16) * Kk + q4 * 8;
    const short* Br1 = Bt + (size_t)(nb + 16 + r16) * Kk + q4 * 8;

    short8 ca0 = *(const short8*)(Ar0);
    short8 ca1 = *(const short8*)(Ar1);
    short8 cb0 = *(const short8*)(Br0);
    short8 cb1 = *(const short8*)(Br1);
    #pragma unroll 4
    for (int k = 32; k <= Kk; k += 32) {
        short8 na0 = ca0, na1 = ca1, nb0 = cb0, nb1 = cb1;
        if (k < Kk) {
            na0 = *(const short8*)(Ar0 + k);
            na1 = *(const short8*)(Ar1 + k);
            nb0 = *(const short8*)(Br0 + k);
            nb1 = *(const short8*)(Br1 + k);
        }
        acc[0][0] = __builtin_amdgcn_mfma_f32_16x16x32_bf16(ca0, cb0, acc[0][0], 0, 0, 0);
        acc[0][1] = __builtin_amdgcn_mfma_f32_16x16x32_bf16(ca0, cb1, acc[0][1], 0, 0, 0);
        acc[1][0] = __builtin_amdgcn_mfma_f32_16x16x32_bf16(ca1, cb0, acc[1][0], 0, 0, 0);
        acc[1][1] = __builtin_amdgcn_mfma_f32_16x16x32_bf16(ca1, cb1, acc[1][1], 0, 0, 0);
        ca0 = na0; ca1 = na1; cb0 = nb0; cb1 = nb1;
    }

    int ofp32 = oflag ? *oflag : 0;
    #pragma unroll
    for (int mt = 0; mt < 2; ++mt) {
        #pragma unroll
        for (int nt = 0; nt < 2; ++nt) {
            int n = nb + nt * 16 + r16;
            float bval = bias ? bf2f(bias[n]) : 0.f;
            #pragma unroll
            for (int r = 0; r < 4; ++r) {
                int m = mb + mt * 16 + q4 * 4 + r;
                float v = acc[mt][nt][r] + bval;
                if (act == 1) v = 0.5f * v * (1.f + erff(v * 0.70710678118f));
                if (res) v += bf2f(res[(size_t)m * Nn + n]);
                size_t oi = (size_t)(m0 + m) * Nn + n;
                if (ofp32) ((float*)Out)[oi] = v;
                else       ((short*)Out)[oi] = f2bf(v);
            }
        }
    }
}

// QKV GEMM: q/k/v written row-major window order. q is pre-scaled via Wq.
template<int BR>
__global__ __launch_bounds__(256) void gemm_qkv_kernel(
    const short* __restrict__ A, const short* __restrict__ Bt,
    short* __restrict__ qw, short* __restrict__ kw, short* __restrict__ vw,
    int t0, int w0)
{
    constexpr int N = (BR == 2) ? 196 : 784;
    int lane = threadIdx.x & 63;
    int wid  = threadIdx.x >> 6;
    int waveM = wid >> 1, waveN = wid & 1;
    int mb = blockIdx.y * 64 + waveM * 32;
    int nb = blockIdx.x * 64 + waveN * 32;
    int r16 = lane & 15, q4 = lane >> 4;

    f32x4 acc[2][2];
    #pragma unroll
    for (int i = 0; i < 2; ++i)
        #pragma unroll
        for (int j = 0; j < 2; ++j)
            acc[i][j] = (f32x4){0.f, 0.f, 0.f, 0.f};

    const short* Ar0 = A  + (size_t)(mb + r16) * 256 + q4 * 8;
    const short* Ar1 = A  + (size_t)(mb + 16 + r16) * 256 + q4 * 8;
    const short* Br0 = Bt + (size_t)(nb + r16) * 256 + q4 * 8;
    const short* Br1 = Bt + (size_t)(nb + 16 + r16) * 256 + q4 * 8;

    short8 ca0 = *(const short8*)(Ar0);
    short8 ca1 = *(const short8*)(Ar1);
    short8 cb0 = *(const short8*)(Br0);
    short8 cb1 = *(const short8*)(Br1);
    #pragma unroll
    for (int k = 32; k <= 256; k += 32) {
        short8 na0 = ca0, na1 = ca1, nb0 = cb0, nb1 = cb1;
        if (k < 256) {
            na0 = *(const short8*)(Ar0 + k);
            na1 = *(const short8*)(Ar1 + k);
            nb0 = *(const short8*)(Br0 + k);
            nb1 = *(const short8*)(Br1 + k);
        }
        acc[0][0] = __builtin_amdgcn_mfma_f32_16x16x32_bf16(ca0, cb0, acc[0][0], 0, 0, 0);
        acc[0][1] = __builtin_amdgcn_mfma_f32_16x16x32_bf16(ca0, cb1, acc[0][1], 0, 0, 0);
        acc[1][0] = __builtin_amdgcn_mfma_f32_16x16x32_bf16(ca1, cb0, acc[1][0], 0, 0, 0);
        acc[1][1] = __builtin_amdgcn_mfma_f32_16x16x32_bf16(ca1, cb1, acc[1][1], 0, 0, 0);
        ca0 = na0; ca1 = na1; cb0 = nb0; cb1 = nb1;
    }

    #pragma unroll
    for (int mt = 0; mt < 2; ++mt) {
        #pragma unroll
        for (int r = 0; r < 4; ++r) {
            int m = mb + mt * 16 + q4 * 4 + r;
            int w, nwin;
            tok2win<BR>(t0 + m, w, nwin);
            size_t row = (size_t)((w - w0) * N + nwin) * 256;
            #pragma unroll
            for (int nt = 0; nt < 2; ++nt) {
                int n = nb + nt * 16 + r16;
                short hv = f2bf(acc[mt][nt][r]);
                if (n < 256)       qw[row + n] = hv;
                else if (n < 512)  kw[row + (n - 256)] = hv;
                else               vw[row + (n - 512)] = hv;
            }
        }
    }
}

// V transpose: vw ([tp,256]) -> vT ([c, w*npad+n]); 28 | 784 and 196.
__global__ __launch_bounds__(256) void vtrans_kernel(
    const short* __restrict__ vw, short* __restrict__ vT,
    int N, int npad, int vstride)
{
    int c = threadIdx.x;
    int tp0 = blockIdx.x * 28;
    int w = tp0 / N, n0 = tp0 - w * N;
    unsigned vals[14];
    #pragma unroll
    for (int r = 0; r < 28; r += 2) {
        unsigned lo = (unsigned short)vw[(size_t)(tp0 + r) * 256 + c];
        unsigned hi = (unsigned short)vw[(size_t)(tp0 + r + 1) * 256 + c];
        vals[r >> 1] = lo | (hi << 16);
    }
    short* dst = vT + (size_t)c * vstride + w * npad + n0;
    #pragma unroll
    for (int i = 0; i < 7; ++i)
        *(uint2v*)(dst + i * 8) = (uint2v){vals[2 * i], vals[2 * i + 1]};
}

// ---------------------------------------------------------------------------
// Flash attention v3: 4 waves/block, each wave one (window, head, 64-row
// q-tile) task with private padded pbuf slice. q pre-scaled; bias via LUT.
// ---------------------------------------------------------------------------
__global__ __launch_bounds__(256) void attn_kernel(
    const short* __restrict__ qw, const short* __restrict__ kw,
    const short* __restrict__ vT, const short* __restrict__ bmat,
    short* __restrict__ aw, int NWIN, int N, int npad, int vstride)
{
    __shared__ alignas(16) short pbuf[4][64 * PSTR];
    int wid = threadIdx.x >> 6, lane = threadIdx.x & 63;
    int QT = (N + 63) >> 6;
    int total = NWIN * NH * QT;
    int task = blockIdx.x * 4 + wid;
    bool valid = task < total;
    if (!valid) task = total - 1;
    int qt = task % QT;
    int t2 = task / QT;
    int h = t2 & 7;
    int w = t2 >> 3;
    int r16 = lane & 15, q4 = lane >> 4;
    int wbase = w * N;
    int vbase = w * npad;
    short* pb = pbuf[wid];

    short8 aq[4];
    #pragma unroll
    for (int j = 0; j < 4; ++j) {
        int qr = qt * 64 + j * 16 + r16; if (qr >= N) qr = N - 1;
        aq[j] = *(const short8*)(qw + (size_t)(wbase + qr) * 256 + h * 32 + q4 * 8);
    }

    f32x4 o[4][2];
    float ps[4][4];
    #pragma unroll
    for (int i = 0; i < 4; ++i) {
        o[i][0] = (f32x4){0.f, 0.f, 0.f, 0.f};
        o[i][1] = (f32x4){0.f, 0.f, 0.f, 0.f};
        #pragma unroll
        for (int r = 0; r < 4; ++r) ps[i][r] = 0.f;
    }
    f32x4 zero = {0.f, 0.f, 0.f, 0.f};
    const short* bh = bmat ? (bmat + (size_t)h * 196 * 196) : nullptr;

    int nch = (N + 31) >> 5;
    for (int kb = 0; kb < nch; ++kb) {
        int kbase = kb * 32;
        int kr0 = kbase + r16;      int kr0c = kr0 < N ? kr0 : N - 1;
        int kr1 = kbase + 16 + r16; int kr1c = kr1 < N ? kr1 : N - 1;
        short8 bk0 = *(const short8*)(kw + (size_t)(wbase + kr0c) * 256 + h * 32 + q4 * 8);
        short8 bk1 = *(const short8*)(kw + (size_t)(wbase + kr1c) * 256 + h * 32 + q4 * 8);
        bool tail = (kbase + 32 > N);

        #pragma unroll
        for (int qi = 0; qi < 4; ++qi) {
            f32x4 s0 = __builtin_amdgcn_mfma_f32_16x16x32_bf16(aq[qi], bk0, zero, 0, 0, 0);
            f32x4 s1 = __builtin_amdgcn_mfma_f32_16x16x32_bf16(aq[qi], bk1, zero, 0, 0, 0);
            if (bh) {
                #pragma unroll
                for (int r = 0; r < 4; ++r) {
                    int n1 = qt * 64 + qi * 16 + q4 * 4 + r; if (n1 >= N) n1 = N - 1;
                    const short* bp = bh + n1 * 196;
                    if (kr0 < N) s0[r] += bf2f(bp[kr0]);
                    if (kr1 < N) s1[r] += bf2f(bp[kr1]);
                }
            }
            if (tail) {
                #pragma unroll
                for (int r = 0; r < 4; ++r) {
                    if (kr0 >= N) s0[r] = -30000.f;
                    if (kr1 >= N) s1[r] = -30000.f;
                }
            }
            #pragma unroll
            for (int r = 0; r < 4; ++r) {
                float e0 = __expf(s0[r]);
                float e1 = __expf(s1[r]);
                ps[qi][r] += e0 + e1;
                int row = qi * 16 + q4 * 4 + r;
                pb[row * PSTR + r16]      = f2bf(e0);
                pb[row * PSTR + 16 + r16] = f2bf(e1);
            }
        }
        __syncthreads();
        short8 bv0 = *(const short8*)(vT + (size_t)(h * 32 + r16) * vstride + vbase + kbase + q4 * 8);
        short8 bv1 = *(const short8*)(vT + (size_t)(h * 32 + 16 + r16) * vstride + vbase + kbase + q4 * 8);
        #pragma unroll
        for (int qi = 0; qi < 4; ++qi) {
            short8 ap = *(const short8*)(pb + (qi * 16 + r16) * PSTR + q4 * 8);
            o[qi][0] = __builtin_amdgcn_mfma_f32_16x16x32_bf16(ap, bv0, o[qi][0], 0, 0, 0);
            o[qi][1] = __builtin_amdgcn_mfma_f32_16x16x32_bf16(ap, bv1, o[qi][1], 0, 0, 0);
        }
        __syncthreads();
    }

    #pragma unroll
    for (int qi = 0; qi < 4; ++qi)
        #pragma unroll
        for (int msk = 1; msk < 16; msk <<= 1)
            #pragma unroll
            for (int r = 0; r < 4; ++r) ps[qi][r] += __shfl_xor(ps[qi][r], msk);

    if (valid) {
        #pragma unroll
        for (int qi = 0; qi < 4; ++qi) {
            #pragma unroll
            for (int r = 0; r < 4; ++r) {
                int n1 = qt * 64 + qi * 16 + q4 * 4 + r;
                if (n1 < N) {
                    float inv = 1.f / fmaxf(ps[qi][r], 1e-20f);
                    size_t row = (size_t)(wbase + n1) * 256;
                    aw[row + h * 32 + r16]      = f2bf(o[qi][0][r] * inv);
                    aw[row + h * 32 + 16 + r16] = f2bf(o[qi][1][r] * inv);
                }
            }
        }
    }
}

__global__ __launch_bounds__(256) void agg_step_kernel(
    const short* __restrict__ xn, const short* __restrict__ pw,
    short* __restrict__ facc, float* __restrict__ mst, float* __restrict__ lst,
    int w0, int N, int branch, int first)
{
    int tp = blockIdx.x * 4 + (threadIdx.x >> 6);
    int lane = threadIdx.x & 63;
    int wl = tp / N, n = tp - wl * N;
    int t = map_t(branch, w0 + wl, n);
    size_t pbase = (size_t)tp * C_DIM + lane * 4;
    size_t tbase = (size_t)t * C_DIM + lane * 4;
    short4v hp = *(const short4v*)(pw + pbase);
    short4v hn = *(const short4v*)(xn + tbase);
    float pv[4], nv[4];
    #pragma unroll
    for (int j = 0; j < 4; ++j) { pv[j] = bf2f(hp[j]); nv[j] = bf2f(hn[j]); }
    float d = pv[0]*nv[0] + pv[1]*nv[1] + pv[2]*nv[2] + pv[3]*nv[3];
    for (int off = 32; off; off >>= 1) d += __shfl_xor(d, off);
    d *= 0.0625f;

    float mo, lo;
    if (first) { mo = -30000.f; lo = 0.f; }
    else       { mo = mst[t];   lo = lst[t]; }
    float mn = fmaxf(mo, d);
    float a  = __expf(mo - mn);
    float e  = __expf(d - mn);
    short4v fo;
    if (first) {
        #pragma unroll
        for (int j = 0; j < 4; ++j) fo[j] = f2bf(e * pv[j]);
    } else {
        short4v hf = *(const short4v*)(facc + tbase);
        #pragma unroll
        for (int j = 0; j < 4; ++j) fo[j] = f2bf(bf2f(hf[j]) * a + e * pv[j]);
    }
    *(short4v*)(facc + tbase) = fo;
    if (lane == 0) { mst[t] = mn; lst[t] = lo * a + e; }
}

__global__ __launch_bounds__(256) void agg_finish_kernel(
    const void* __restrict__ x, short* __restrict__ facc,
    const float* __restrict__ lst, short* __restrict__ xn,
    const short* __restrict__ g2, const short* __restrict__ b2,
    const int* __restrict__ flag)
{
    int t = blockIdx.x * 4 + (threadIdx.x >> 6);
    int lane = threadIdx.x & 63;
    size_t base = (size_t)t * C_DIM + lane * 4;
    float vx[4];
    if (*flag) {
        f32x4 hv = *(const f32x4*)((const float*)x + base);
        #pragma unroll
        for (int j = 0; j < 4; ++j) vx[j] = hv[j];
    } else {
        short4v hv = *(const short4v*)((const short*)x + base);
        #pragma unroll
        for (int j = 0; j < 4; ++j) vx[j] = bf2f(hv[j]);
    }
    short4v hf = *(const short4v*)(facc + base);
    float linv = 1.f / fmaxf(lst[t], 1e-20f);
    float vy[4];
    #pragma unroll
    for (int j = 0; j < 4; ++j) vy[j] = vx[j] + bf2f(hf[j]) * linv;
    float s = 0.f, ss = 0.f;
    #pragma unroll
    for (int j = 0; j < 4; ++j) { s += vy[j]; ss += vy[j] * vy[j]; }
    for (int off = 32; off; off >>= 1) {
        s  += __shfl_xor(s, off);
        ss += __shfl_xor(ss, off);
    }
    float mean = s * (1.f / 256.f);
    float var  = fmaxf(ss * (1.f / 256.f) - mean * mean, 0.f);
    float rstd = rsqrtf(var + 1e-5f);
    short4v hg = *(const short4v*)(g2 + lane * 4);
    short4v hb = *(const short4v*)(b2 + lane * 4);
    short4v oy, on;
    #pragma unroll
    for (int j = 0; j < 4; ++j) {
        oy[j] = f2bf(vy[j]);
        on[j] = f2bf((vy[j] - mean) * rstd * bf2f(hg[j]) + bf2f(hb[j]));
    }
    *(short4v*)(facc + base) = oy;
    *(short4v*)(xn   + base) = on;
}

extern "C" void kernel_launch(void* const* d_in, const int* in_sizes, int n_in,
                              void* d_out, int out_size, void* d_ws, size_t ws_size,
                              hipStream_t stream)
{
    const void* x   = d_in[0];
    const void* g1r = d_in[1];
    const void* b1r = d_in[2];
    const void* g2r = d_in[3];
    const void* b2r = d_in[4];
    const void* wqkv[3]   = {d_in[5], d_in[8],  d_in[11]};
    const void* wproj[3]  = {d_in[6], d_in[9],  d_in[12]};
    const void* bprojr[3] = {d_in[7], d_in[10], d_in[13]};
    const void* rpbr  = d_in[14];
    const void* wfc1  = d_in[15];
    const void* bfc1r = d_in[16];
    const void* wfc2  = d_in[17];
    const void* bfc2r = d_in[18];

    char* ws = (char*)d_ws;
    size_t off = 0;
    auto give = [&](size_t bytes) -> char* {
        char* p = ws + off;
        off += (bytes + 255) & ~(size_t)255;
        return p;
    };
    int*   flag = (int*)give(256);
    short* xn   = (short*)give((size_t)M_TOK * C_DIM * 2);
    short* facc = (short*)give((size_t)M_TOK * C_DIM * 2);
    float* mst  = (float*)give((size_t)M_TOK * 4);
    float* lst  = (float*)give((size_t)M_TOK * 4);
    short* g1 = (short*)give(256 * 2), *b1 = (short*)give(256 * 2);
    short* g2 = (short*)give(256 * 2), *b2 = (short*)give(256 * 2);
    short* bproj[3];
    for (int i = 0; i < 3; ++i) bproj[i] = (short*)give(256 * 2);
    short* bfc1 = (short*)give(1024 * 2), *bfc2 = (short*)give(256 * 2);
    short* rpb  = (short*)give(729 * 8 * 2);
    short* bmat = (short*)give((size_t)8 * 196 * 196 * 2);
    short* wqkvT[3], *wprojT[3];
    for (int i = 0; i < 3; ++i) wqkvT[i]  = (short*)give(768 * 256 * 2);
    for (int i = 0; i < 3; ++i) wprojT[i] = (short*)give(256 * 256 * 2);
    short* fc1T = (short*)give(1024 * 256 * 2);
    short* fc2T = (short*)give(256 * 1024 * 2);
    char*  trans = give(26u * 1024 * 1024);

    const float scale = 0.17677669529663687f;   // 1/sqrt(32), folded into Wq

    detect_kernel<<<1, 64, 0, stream>>>((const unsigned*)g1r, flag);
    convert_kernel<<<1, 256, 0, stream>>>(g1r, g1, 256, flag);
    convert_kernel<<<1, 256, 0, stream>>>(b1r, b1, 256, flag);
    convert_kernel<<<1, 256, 0, stream>>>(g2r, g2, 256, flag);
    convert_kernel<<<1, 256, 0, stream>>>(b2r, b2, 256, flag);
    for (int i = 0; i < 3; ++i)
        convert_kernel<<<1, 256, 0, stream>>>(bprojr[i], bproj[i], 256, flag);
    convert_kernel<<<4, 256, 0, stream>>>(bfc1r, bfc1, 1024, flag);
    convert_kernel<<<1, 256, 0, stream>>>(bfc2r, bfc2, 256, flag);
    convert_kernel<<<23, 256, 0, stream>>>(rpbr, rpb, 729 * 8, flag);
    biasmat_kernel<<<(8 * 196 * 196 + 255) / 256, 256, 0, stream>>>(rpb, bmat);

    for (int i = 0; i < 3; ++i) {
        transpose_kernel<<<dim3(24, 8), dim3(32, 8), 0, stream>>>(wqkv[i], wqkvT[i], 256, 768, flag, 256, scale);
        transpose_kernel<<<dim3(8, 8),  dim3(32, 8), 0, stream>>>(wproj[i], wprojT[i], 256, 256, flag, 0, 1.f);
    }
    transpose_kernel<<<dim3(32, 8), dim3(32, 8), 0, stream>>>(wfc1, fc1T, 256, 1024, flag, 0, 1.f);
    transpose_kernel<<<dim3(8, 32), dim3(32, 8), 0, stream>>>(wfc2, fc2T, 1024, 256, flag, 0, 1.f);

    ln_kernel<<<M_TOK / 4, 256, 0, stream>>>(x, g1, b1, xn, flag);

    for (int br = 0; br < 3; ++br) {
        const int N      = (br == 2) ? 196 : 784;
        const int NPAD   = (br == 2) ? 224 : 800;
        const int NCHUNK = (br == 2) ? 4 : 2;
        const int WPER   = (br == 2) ? 32 : 16;
        const int CHM    = (br == 2) ? 6272 : 12544;
        const int VSTR   = WPER * NPAD;
        for (int c = 0; c < NCHUNK; ++c) {
            int t0 = c * CHM;
            int w0 = c * WPER;
            short* qw = (short*)trans;
            short* kw = qw + (size_t)CHM * C_DIM;
            short* vw = kw + (size_t)CHM * C_DIM;   // aliased by aw after vtrans
            short* vT = vw + (size_t)CHM * C_DIM;
            short* aw = vw;
            dim3 qg(12, CHM / 64);
            if (br == 0)      gemm_qkv_kernel<0><<<qg, 256, 0, stream>>>(xn + (size_t)t0 * C_DIM, wqkvT[0], qw, kw, vw, t0, w0);
            else if (br == 1) gemm_qkv_kernel<1><<<qg, 256, 0, stream>>>(xn + (size_t)t0 * C_DIM, wqkvT[1], qw, kw, vw, t0, w0);
            else              gemm_qkv_kernel<2><<<qg, 256, 0, stream>>>(xn + (size_t)t0 * C_DIM, wqkvT[2], qw, kw, vw, t0, w0);
            vtrans_kernel<<<CHM / 28, 256, 0, stream>>>(vw, vT, N, NPAD, VSTR);
            int QT = (N + 63) >> 6;
            int tasks = WPER * NH * QT;
            attn_kernel<<<(tasks + 3) / 4, 256, 0, stream>>>(
                qw, kw, vT, (br == 2) ? bmat : nullptr, aw, WPER, N, NPAD, VSTR);
            gemm_kernel<<<dim3(4, CHM / 64), 256, 0, stream>>>(
                aw, wprojT[br], qw, 0, 256, 256, bproj[br], 0, nullptr, nullptr);
            agg_step_kernel<<<CHM / 4, 256, 0, stream>>>(
                xn, qw, facc, mst, lst, w0, N, br, br == 0 ? 1 : 0);
        }
    }

    agg_finish_kernel<<<M_TOK / 4, 256, 0, stream>>>(x, facc, lst, xn, g2, b2, flag);

    short* hbuf = (short*)trans;
    for (int q = 0; q < 4; ++q) {
        size_t ro = (size_t)q * 6272;
        gemm_kernel<<<dim3(16, 98), 256, 0, stream>>>(
            xn + ro * C_DIM, fc1T, hbuf, 0, HID_DIM, 256, bfc1, 1, nullptr, nullptr);
        gemm_kernel<<<dim3(4, 98), 256, 0, stream>>>(
            hbuf, fc2T, d_out, (int)ro, 256, HID_DIM, bfc2, 0,
            facc + ro * C_DIM, flag);
    }
}

// Round 8
// 1198.603 us; speedup vs baseline: 1.1431x; 1.1431x over previous
//
#include <hip/hip_runtime.h>
#include <hip/hip_bf16.h>

#define M_TOK   25088
#define C_DIM   256
#define NH      8
#define HID_DIM 1024
#define PSTR    40          // pbuf row stride in shorts (80B: b128-aligned, 2-way banks = free)

typedef __attribute__((ext_vector_type(8))) short short8;
typedef __attribute__((ext_vector_type(4))) short short4v;
typedef __attribute__((ext_vector_type(4))) float f32x4;
typedef __attribute__((ext_vector_type(2))) unsigned uint2v;

__device__ __forceinline__ short f2bf(float f) {
    return __builtin_bit_cast(short, __float2bfloat16(f));
}
__device__ __forceinline__ float bf2f(short s) {
    return __bfloat162float(__builtin_bit_cast(__hip_bfloat16, s));
}

__device__ __forceinline__ int map_t(int branch, int w, int n) {
    if (branch == 0) {
        return w * 784 + n;
    } else if (branch == 1) {
        int b = w >> 4, wc = w & 15;
        int h2 = n / 7, s = n - h2 * 7;
        return b * 12544 + h2 * 112 + wc * 7 + s;
    } else {
        int b = w >> 6, wi = w & 63;
        int wh = wi >> 3, ww = wi & 7;
        int i = n / 14, j = n - i * 14;
        return b * 12544 + (wh * 14 + i) * 112 + ww * 14 + j;
    }
}

template<int BR>
__device__ __forceinline__ void tok2win(int t, int& w, int& n) {
    if constexpr (BR == 0) {
        w = t / 784; n = t - w * 784;
    } else if constexpr (BR == 1) {
        int b = t / 12544, r = t - b * 12544;
        int h2 = r / 112, cc = r - h2 * 112;
        int wc = cc / 7, s = cc - wc * 7;
        w = b * 16 + wc; n = h2 * 7 + s;
    } else {
        int b = t / 12544, r = t - b * 12544;
        int ii = r / 112, jj = r - ii * 112;
        int wh = ii / 14, i = ii - wh * 14;
        int ww = jj / 14, j = jj - ww * 14;
        w = b * 64 + wh * 8 + ww; n = i * 14 + j;
    }
}

__global__ void detect_kernel(const unsigned* __restrict__ g1, int* flag) {
    if (threadIdx.x == 0) *flag = (g1[0] == 0x3F800000u) ? 1 : 0;
}

// One fused conversion pass for all 9 small tensors
struct PrepArgs {
    const void* src[9];
    short* dst[9];
    int n[9];
};
__global__ void prep_kernel(PrepArgs a, const int* __restrict__ flag) {
    int i = blockIdx.x * 256 + threadIdx.x;
    int fp32 = *flag;
    #pragma unroll
    for (int s = 0; s < 9; ++s) {
        if (i < a.n[s]) {
            a.dst[s][i] = fp32 ? f2bf(((const float*)a.src[s])[i])
                               : ((const short*)a.src[s])[i];
            return;
        }
        i -= a.n[s];
    }
}

// Precompute attn3 bias matrix from RAW rpb: bmat[h][n1][n2] (bf16)
__global__ void biasmat_kernel(const void* __restrict__ rpbr,
                               short* __restrict__ bmat,
                               const int* __restrict__ flag) {
    int idx = blockIdx.x * 256 + threadIdx.x;
    if (idx >= 8 * 196 * 196) return;
    int h = idx / 38416, rest = idx - h * 38416;
    int n1 = rest / 196, n2 = rest - n1 * 196;
    int i1 = n1 / 14, j1 = n1 - i1 * 14;
    int i2 = n2 / 14, j2 = n2 - i2 * 14;
    int src = ((i1 - i2 + 13) * 27 + (j1 - j2 + 13)) * 8 + h;
    bmat[idx] = *flag ? f2bf(((const float*)rpbr)[src]) : ((const short*)rpbr)[src];
}

__global__ __launch_bounds__(256) void ln_kernel(
    const void* __restrict__ x, const short* __restrict__ g,
    const short* __restrict__ b, short* __restrict__ out,
    const int* __restrict__ flag)
{
    int t = blockIdx.x * 4 + (threadIdx.x >> 6);
    int lane = threadIdx.x & 63;
    size_t base = (size_t)t * C_DIM + lane * 4;
    float v[4];
    if (*flag) {
        f32x4 hv = *(const f32x4*)((const float*)x + base);
        #pragma unroll
        for (int j = 0; j < 4; ++j) v[j] = hv[j];
    } else {
        short4v hv = *(const short4v*)((const short*)x + base);
        #pragma unroll
        for (int j = 0; j < 4; ++j) v[j] = bf2f(hv[j]);
    }
    float s = v[0] + v[1] + v[2] + v[3];
    float ss = v[0]*v[0] + v[1]*v[1] + v[2]*v[2] + v[3]*v[3];
    for (int off = 32; off; off >>= 1) {
        s  += __shfl_xor(s, off);
        ss += __shfl_xor(ss, off);
    }
    float mean = s * (1.f / 256.f);
    float var  = fmaxf(ss * (1.f / 256.f) - mean * mean, 0.f);
    float rstd = rsqrtf(var + 1e-5f);
    short4v hg = *(const short4v*)(g + lane * 4);
    short4v hb = *(const short4v*)(b + lane * 4);
    short4v o;
    #pragma unroll
    for (int j = 0; j < 4; ++j)
        o[j] = f2bf((v[j] - mean) * rstd * bf2f(hg[j]) + bf2f(hb[j]));
    *(short4v*)(out + base) = o;
}

// Transpose + optional column prescale (src cols < scaleCols get * smul)
__global__ void transpose_kernel(const void* __restrict__ src,
                                 short* __restrict__ dst, int R, int Cc,
                                 const int* __restrict__ flag,
                                 int scaleCols, float smul)
{
    __shared__ short tile[32][33];
    int c0 = blockIdx.x * 32, r0 = blockIdx.y * 32;
    int tx = threadIdx.x, ty = threadIdx.y;
    int fp32 = *flag;
    #pragma unroll
    for (int i = 0; i < 32; i += 8) {
        int r = r0 + ty + i, c = c0 + tx;
        if (r < R && c < Cc) {
            size_t idx = (size_t)r * Cc + c;
            float v = fp32 ? ((const float*)src)[idx] : bf2f(((const short*)src)[idx]);
            if (c < scaleCols) v *= smul;
            tile[ty + i][tx] = f2bf(v);
        }
    }
    __syncthreads();
    #pragma unroll
    for (int i = 0; i < 32; i += 8) {
        int r = c0 + ty + i, c = r0 + tx;
        if (r < Cc && c < R) dst[(size_t)r * R + c] = tile[tx][ty + i];
    }
}

// Out row index = m0 + local m. oflag: null->bf16 out; else dtype per *oflag.
__global__ __launch_bounds__(256) void gemm_kernel(
    const short* __restrict__ A, const short* __restrict__ Bt,
    void* __restrict__ Out, int m0, int Nn, int Kk,
    const short* __restrict__ bias, int act, const short* __restrict__ res,
    const int* __restrict__ oflag)
{
    int lane = threadIdx.x & 63;
    int wid  = threadIdx.x >> 6;
    int waveM = wid >> 1, waveN = wid & 1;
    int mb = blockIdx.y * 64 + waveM * 32;
    int nb = blockIdx.x * 64 + waveN * 32;
    int r16 = lane & 15, q4 = lane >> 4;

    f32x4 acc[2][2];
    #pragma unroll
    for (int i = 0; i < 2; ++i)
        #pragma unroll
        for (int j = 0; j < 2; ++j)
            acc[i][j] = (f32x4){0.f, 0.f, 0.f, 0.f};

    const short* Ar0 = A  + (size_t)(mb + r16) * Kk + q4 * 8;
    const short* Ar1 = A  + (size_t)(mb + 16 + r16) * Kk + q4 * 8;
    const short* Br0 = Bt + (size_t)(nb + r16) * Kk + q4 * 8;
    const short* Br1 = Bt + (size_t)(nb + 16 + r16) * Kk + q4 * 8;

    short8 ca0 = *(const short8*)(Ar0);
    short8 ca1 = *(const short8*)(Ar1);
    short8 cb0 = *(const short8*)(Br0);
    short8 cb1 = *(const short8*)(Br1);
    #pragma unroll 4
    for (int k = 32; k <= Kk; k += 32) {
        short8 na0 = ca0, na1 = ca1, nb0 = cb0, nb1 = cb1;
        if (k < Kk) {
            na0 = *(const short8*)(Ar0 + k);
            na1 = *(const short8*)(Ar1 + k);
            nb0 = *(const short8*)(Br0 + k);
            nb1 = *(const short8*)(Br1 + k);
        }
        acc[0][0] = __builtin_amdgcn_mfma_f32_16x16x32_bf16(ca0, cb0, acc[0][0], 0, 0, 0);
        acc[0][1] = __builtin_amdgcn_mfma_f32_16x16x32_bf16(ca0, cb1, acc[0][1], 0, 0, 0);
        acc[1][0] = __builtin_amdgcn_mfma_f32_16x16x32_bf16(ca1, cb0, acc[1][0], 0, 0, 0);
        acc[1][1] = __builtin_amdgcn_mfma_f32_16x16x32_bf16(ca1, cb1, acc[1][1], 0, 0, 0);
        ca0 = na0; ca1 = na1; cb0 = nb0; cb1 = nb1;
    }

    int ofp32 = oflag ? *oflag : 0;
    #pragma unroll
    for (int mt = 0; mt < 2; ++mt) {
        #pragma unroll
        for (int nt = 0; nt < 2; ++nt) {
            int n = nb + nt * 16 + r16;
            float bval = bias ? bf2f(bias[n]) : 0.f;
            #pragma unroll
            for (int r = 0; r < 4; ++r) {
                int m = mb + mt * 16 + q4 * 4 + r;
                float v = acc[mt][nt][r] + bval;
                if (act == 1) v = 0.5f * v * (1.f + erff(v * 0.70710678118f));
                if (res) v += bf2f(res[(size_t)m * Nn + n]);
                size_t oi = (size_t)(m0 + m) * Nn + n;
                if (ofp32) ((float*)Out)[oi] = v;
                else       ((short*)Out)[oi] = f2bf(v);
            }
        }
    }
}

// QKV GEMM: q/k/v written row-major window order. q is pre-scaled via Wq.
template<int BR>
__global__ __launch_bounds__(256) void gemm_qkv_kernel(
    const short* __restrict__ A, const short* __restrict__ Bt,
    short* __restrict__ qw, short* __restrict__ kw, short* __restrict__ vw,
    int t0, int w0)
{
    constexpr int N = (BR == 2) ? 196 : 784;
    int lane = threadIdx.x & 63;
    int wid  = threadIdx.x >> 6;
    int waveM = wid >> 1, waveN = wid & 1;
    int mb = blockIdx.y * 64 + waveM * 32;
    int nb = blockIdx.x * 64 + waveN * 32;
    int r16 = lane & 15, q4 = lane >> 4;

    f32x4 acc[2][2];
    #pragma unroll
    for (int i = 0; i < 2; ++i)
        #pragma unroll
        for (int j = 0; j < 2; ++j)
            acc[i][j] = (f32x4){0.f, 0.f, 0.f, 0.f};

    const short* Ar0 = A  + (size_t)(mb + r16) * 256 + q4 * 8;
    const short* Ar1 = A  + (size_t)(mb + 16 + r16) * 256 + q4 * 8;
    const short* Br0 = Bt + (size_t)(nb + r16) * 256 + q4 * 8;
    const short* Br1 = Bt + (size_t)(nb + 16 + r16) * 256 + q4 * 8;

    short8 ca0 = *(const short8*)(Ar0);
    short8 ca1 = *(const short8*)(Ar1);
    short8 cb0 = *(const short8*)(Br0);
    short8 cb1 = *(const short8*)(Br1);
    #pragma unroll
    for (int k = 32; k <= 256; k += 32) {
        short8 na0 = ca0, na1 = ca1, nb0 = cb0, nb1 = cb1;
        if (k < 256) {
            na0 = *(const short8*)(Ar0 + k);
            na1 = *(const short8*)(Ar1 + k);
            nb0 = *(const short8*)(Br0 + k);
            nb1 = *(const short8*)(Br1 + k);
        }
        acc[0][0] = __builtin_amdgcn_mfma_f32_16x16x32_bf16(ca0, cb0, acc[0][0], 0, 0, 0);
        acc[0][1] = __builtin_amdgcn_mfma_f32_16x16x32_bf16(ca0, cb1, acc[0][1], 0, 0, 0);
        acc[1][0] = __builtin_amdgcn_mfma_f32_16x16x32_bf16(ca1, cb0, acc[1][0], 0, 0, 0);
        acc[1][1] = __builtin_amdgcn_mfma_f32_16x16x32_bf16(ca1, cb1, acc[1][1], 0, 0, 0);
        ca0 = na0; ca1 = na1; cb0 = nb0; cb1 = nb1;
    }

    #pragma unroll
    for (int mt = 0; mt < 2; ++mt) {
        #pragma unroll
        for (int r = 0; r < 4; ++r) {
            int m = mb + mt * 16 + q4 * 4 + r;
            int w, nwin;
            tok2win<BR>(t0 + m, w, nwin);
            size_t row = (size_t)((w - w0) * N + nwin) * 256;
            #pragma unroll
            for (int nt = 0; nt < 2; ++nt) {
                int n = nb + nt * 16 + r16;
                short hv = f2bf(acc[mt][nt][r]);
                if (n < 256)       qw[row + n] = hv;
                else if (n < 512)  kw[row + (n - 256)] = hv;
                else               vw[row + (n - 512)] = hv;
            }
        }
    }
}

// V transpose: vw ([tp,256]) -> vT ([c, w*npad+n]); 28 | 784 and 196.
__global__ __launch_bounds__(256) void vtrans_kernel(
    const short* __restrict__ vw, short* __restrict__ vT,
    int N, int npad, int vstride)
{
    int c = threadIdx.x;
    int tp0 = blockIdx.x * 28;
    int w = tp0 / N, n0 = tp0 - w * N;
    unsigned vals[14];
    #pragma unroll
    for (int r = 0; r < 28; r += 2) {
        unsigned lo = (unsigned short)vw[(size_t)(tp0 + r) * 256 + c];
        unsigned hi = (unsigned short)vw[(size_t)(tp0 + r + 1) * 256 + c];
        vals[r >> 1] = lo | (hi << 16);
    }
    short* dst = vT + (size_t)c * vstride + w * npad + n0;
    #pragma unroll
    for (int i = 0; i < 7; ++i)
        *(uint2v*)(dst + i * 8) = (uint2v){vals[2 * i], vals[2 * i + 1]};
}

// ---------------------------------------------------------------------------
// Flash attention v4: 4 INDEPENDENT waves/block (no s_barrier), 32-row
// q-tiles, wave-private padded pbuf, 2-stage K/V register prefetch.
// Wave-local LDS ordering: CDNA DS ops from one wave execute in order;
// wave_barrier() pins compiler ordering (zero HW cost).
// ---------------------------------------------------------------------------
__global__ __launch_bounds__(256) void attn_kernel(
    const short* __restrict__ qw, const short* __restrict__ kw,
    const short* __restrict__ vT, const short* __restrict__ bmat,
    short* __restrict__ aw, int NWIN, int N, int npad, int vstride)
{
    __shared__ alignas(16) short pbuf[4][32 * PSTR];
    int wid = threadIdx.x >> 6, lane = threadIdx.x & 63;
    int QT = (N + 31) >> 5;
    int total = NWIN * NH * QT;
    int task = blockIdx.x * 4 + wid;
    bool valid = task < total;
    if (!valid) task = total - 1;
    int qt = task % QT;
    int t2 = task / QT;
    int h = t2 & 7;
    int w = t2 >> 3;
    int r16 = lane & 15, q4 = lane >> 4;
    int wbase = w * N, vbase = w * npad;
    short* pb = pbuf[wid];

    int qr0 = qt * 32 + r16;      if (qr0 >= N) qr0 = N - 1;
    int qr1 = qt * 32 + 16 + r16; if (qr1 >= N) qr1 = N - 1;
    short8 aq0 = *(const short8*)(qw + (size_t)(wbase + qr0) * 256 + h * 32 + q4 * 8);
    short8 aq1 = *(const short8*)(qw + (size_t)(wbase + qr1) * 256 + h * 32 + q4 * 8);

    f32x4 o00 = {0.f,0.f,0.f,0.f}, o01 = o00, o10 = o00, o11 = o00;
    float ps0[4] = {0.f,0.f,0.f,0.f}, ps1[4] = {0.f,0.f,0.f,0.f};
    const short* bh = bmat ? bmat + (size_t)h * 38416 : nullptr;
    const short* krow  = kw + (size_t)wbase * 256 + h * 32 + q4 * 8;
    const short* vrow0 = vT + (size_t)(h * 32 + r16) * vstride + vbase + q4 * 8;
    const short* vrow1 = vT + (size_t)(h * 32 + 16 + r16) * vstride + vbase + q4 * 8;
    f32x4 zero = {0.f,0.f,0.f,0.f};

    int nch = (N + 31) >> 5;
    short8 bk0, bk1, bv0, bv1;
    {
        int c1 = 16 + r16; if (c1 >= N) c1 = N - 1;
        bk0 = *(const short8*)(krow + (size_t)r16 * 256);
        bk1 = *(const short8*)(krow + (size_t)c1 * 256);
        bv0 = *(const short8*)(vrow0);
        bv1 = *(const short8*)(vrow1);
    }
    for (int kb = 0; kb < nch; ++kb) {
        int kbase = kb * 32;
        short8 nk0 = bk0, nk1 = bk1, nv0 = bv0, nv1 = bv1;
        if (kb + 1 < nch) {
            int kn = kbase + 32;
            int c0 = kn + r16;      if (c0 >= N) c0 = N - 1;
            int c1 = kn + 16 + r16; if (c1 >= N) c1 = N - 1;
            nk0 = *(const short8*)(krow + (size_t)c0 * 256);
            nk1 = *(const short8*)(krow + (size_t)c1 * 256);
            nv0 = *(const short8*)(vrow0 + kn);
            nv1 = *(const short8*)(vrow1 + kn);
        }
        f32x4 s00 = __builtin_amdgcn_mfma_f32_16x16x32_bf16(aq0, bk0, zero, 0, 0, 0);
        f32x4 s01 = __builtin_amdgcn_mfma_f32_16x16x32_bf16(aq0, bk1, zero, 0, 0, 0);
        f32x4 s10 = __builtin_amdgcn_mfma_f32_16x16x32_bf16(aq1, bk0, zero, 0, 0, 0);
        f32x4 s11 = __builtin_amdgcn_mfma_f32_16x16x32_bf16(aq1, bk1, zero, 0, 0, 0);
        int kr0 = kbase + r16, kr1 = kbase + 16 + r16;

        if (bh) {
            #pragma unroll
            for (int r = 0; r < 4; ++r) {
                int n1a = qt * 32 + q4 * 4 + r;      if (n1a >= N) n1a = N - 1;
                int n1b = qt * 32 + 16 + q4 * 4 + r; if (n1b >= N) n1b = N - 1;
                const short* bpa = bh + n1a * 196;
                const short* bpb = bh + n1b * 196;
                if (kr0 < N) { s00[r] += bf2f(bpa[kr0]); s10[r] += bf2f(bpb[kr0]); }
                if (kr1 < N) { s01[r] += bf2f(bpa[kr1]); s11[r] += bf2f(bpb[kr1]); }
            }
        }
        if (kbase + 32 > N) {
            #pragma unroll
            for (int r = 0; r < 4; ++r) {
                if (kr0 >= N) { s00[r] = -30000.f; s10[r] = -30000.f; }
                if (kr1 >= N) { s01[r] = -30000.f; s11[r] = -30000.f; }
            }
        }

        #pragma unroll
        for (int r = 0; r < 4; ++r) {
            int ra = (q4 * 4 + r) * PSTR, rb = (16 + q4 * 4 + r) * PSTR;
            float e;
            e = __expf(s00[r]); ps0[r] += e; pb[ra + r16]      = f2bf(e);
            e = __expf(s01[r]); ps0[r] += e; pb[ra + 16 + r16] = f2bf(e);
            e = __expf(s10[r]); ps1[r] += e; pb[rb + r16]      = f2bf(e);
            e = __expf(s11[r]); ps1[r] += e; pb[rb + 16 + r16] = f2bf(e);
        }
        __builtin_amdgcn_wave_barrier();   // writes stay before reads
        short8 ap0 = *(const short8*)(pb + r16 * PSTR + q4 * 8);
        short8 ap1 = *(const short8*)(pb + (16 + r16) * PSTR + q4 * 8);
        __builtin_amdgcn_wave_barrier();   // reads stay before next-iter writes
        o00 = __builtin_amdgcn_mfma_f32_16x16x32_bf16(ap0, bv0, o00, 0, 0, 0);
        o01 = __builtin_amdgcn_mfma_f32_16x16x32_bf16(ap0, bv1, o01, 0, 0, 0);
        o10 = __builtin_amdgcn_mfma_f32_16x16x32_bf16(ap1, bv0, o10, 0, 0, 0);
        o11 = __builtin_amdgcn_mfma_f32_16x16x32_bf16(ap1, bv1, o11, 0, 0, 0);
        bk0 = nk0; bk1 = nk1; bv0 = nv0; bv1 = nv1;
    }

    #pragma unroll
    for (int msk = 1; msk < 16; msk <<= 1)
        #pragma unroll
        for (int r = 0; r < 4; ++r) {
            ps0[r] += __shfl_xor(ps0[r], msk);
            ps1[r] += __shfl_xor(ps1[r], msk);
        }

    if (valid) {
        #pragma unroll
        for (int r = 0; r < 4; ++r) {
            int n1 = qt * 32 + q4 * 4 + r;
            if (n1 < N) {
                float inv = 1.f / fmaxf(ps0[r], 1e-20f);
                size_t row = (size_t)(wbase + n1) * 256;
                aw[row + h * 32 + r16]      = f2bf(o00[r] * inv);
                aw[row + h * 32 + 16 + r16] = f2bf(o01[r] * inv);
            }
            int n2 = qt * 32 + 16 + q4 * 4 + r;
            if (n2 < N) {
                float inv = 1.f / fmaxf(ps1[r], 1e-20f);
                size_t row = (size_t)(wbase + n2) * 256;
                aw[row + h * 32 + r16]      = f2bf(o10[r] * inv);
                aw[row + h * 32 + 16 + r16] = f2bf(o11[r] * inv);
            }
        }
    }
}

__global__ __launch_bounds__(256) void agg_step_kernel(
    const short* __restrict__ xn, const short* __restrict__ pw,
    short* __restrict__ facc, float* __restrict__ mst, float* __restrict__ lst,
    int w0, int N, int branch, int first)
{
    int tp = blockIdx.x * 4 + (threadIdx.x >> 6);
    int lane = threadIdx.x & 63;
    int wl = tp / N, n = tp - wl * N;
    int t = map_t(branch, w0 + wl, n);
    size_t pbase = (size_t)tp * C_DIM + lane * 4;
    size_t tbase = (size_t)t * C_DIM + lane * 4;
    short4v hp = *(const short4v*)(pw + pbase);
    short4v hn = *(const short4v*)(xn + tbase);
    float pv[4], nv[4];
    #pragma unroll
    for (int j = 0; j < 4; ++j) { pv[j] = bf2f(hp[j]); nv[j] = bf2f(hn[j]); }
    float d = pv[0]*nv[0] + pv[1]*nv[1] + pv[2]*nv[2] + pv[3]*nv[3];
    for (int off = 32; off; off >>= 1) d += __shfl_xor(d, off);
    d *= 0.0625f;

    float mo, lo;
    if (first) { mo = -30000.f; lo = 0.f; }
    else       { mo = mst[t];   lo = lst[t]; }
    float mn = fmaxf(mo, d);
    float a  = __expf(mo - mn);
    float e  = __expf(d - mn);
    short4v fo;
    if (first) {
        #pragma unroll
        for (int j = 0; j < 4; ++j) fo[j] = f2bf(e * pv[j]);
    } else {
        short4v hf = *(const short4v*)(facc + tbase);
        #pragma unroll
        for (int j = 0; j < 4; ++j) fo[j] = f2bf(bf2f(hf[j]) * a + e * pv[j]);
    }
    *(short4v*)(facc + tbase) = fo;
    if (lane == 0) { mst[t] = mn; lst[t] = lo * a + e; }
}

__global__ __launch_bounds__(256) void agg_finish_kernel(
    const void* __restrict__ x, short* __restrict__ facc,
    const float* __restrict__ lst, short* __restrict__ xn,
    const short* __restrict__ g2, const short* __restrict__ b2,
    const int* __restrict__ flag)
{
    int t = blockIdx.x * 4 + (threadIdx.x >> 6);
    int lane = threadIdx.x & 63;
    size_t base = (size_t)t * C_DIM + lane * 4;
    float vx[4];
    if (*flag) {
        f32x4 hv = *(const f32x4*)((const float*)x + base);
        #pragma unroll
        for (int j = 0; j < 4; ++j) vx[j] = hv[j];
    } else {
        short4v hv = *(const short4v*)((const short*)x + base);
        #pragma unroll
        for (int j = 0; j < 4; ++j) vx[j] = bf2f(hv[j]);
    }
    short4v hf = *(const short4v*)(facc + base);
    float linv = 1.f / fmaxf(lst[t], 1e-20f);
    float vy[4];
    #pragma unroll
    for (int j = 0; j < 4; ++j) vy[j] = vx[j] + bf2f(hf[j]) * linv;
    float s = 0.f, ss = 0.f;
    #pragma unroll
    for (int j = 0; j < 4; ++j) { s += vy[j]; ss += vy[j] * vy[j]; }
    for (int off = 32; off; off >>= 1) {
        s  += __shfl_xor(s, off);
        ss += __shfl_xor(ss, off);
    }
    float mean = s * (1.f / 256.f);
    float var  = fmaxf(ss * (1.f / 256.f) - mean * mean, 0.f);
    float rstd = rsqrtf(var + 1e-5f);
    short4v hg = *(const short4v*)(g2 + lane * 4);
    short4v hb = *(const short4v*)(b2 + lane * 4);
    short4v oy, on;
    #pragma unroll
    for (int j = 0; j < 4; ++j) {
        oy[j] = f2bf(vy[j]);
        on[j] = f2bf((vy[j] - mean) * rstd * bf2f(hg[j]) + bf2f(hb[j]));
    }
    *(short4v*)(facc + base) = oy;
    *(short4v*)(xn   + base) = on;
}

extern "C" void kernel_launch(void* const* d_in, const int* in_sizes, int n_in,
                              void* d_out, int out_size, void* d_ws, size_t ws_size,
                              hipStream_t stream)
{
    const void* x   = d_in[0];
    const void* g1r = d_in[1];
    const void* b1r = d_in[2];
    const void* g2r = d_in[3];
    const void* b2r = d_in[4];
    const void* wqkv[3]   = {d_in[5], d_in[8],  d_in[11]};
    const void* wproj[3]  = {d_in[6], d_in[9],  d_in[12]};
    const void* bprojr[3] = {d_in[7], d_in[10], d_in[13]};
    const void* rpbr  = d_in[14];
    const void* wfc1  = d_in[15];
    const void* bfc1r = d_in[16];
    const void* wfc2  = d_in[17];
    const void* bfc2r = d_in[18];

    char* ws = (char*)d_ws;
    size_t off = 0;
    auto give = [&](size_t bytes) -> char* {
        char* p = ws + off;
        off += (bytes + 255) & ~(size_t)255;
        return p;
    };
    int*   flag = (int*)give(256);
    short* xn   = (short*)give((size_t)M_TOK * C_DIM * 2);
    short* facc = (short*)give((size_t)M_TOK * C_DIM * 2);
    float* mst  = (float*)give((size_t)M_TOK * 4);
    float* lst  = (float*)give((size_t)M_TOK * 4);
    short* g1 = (short*)give(256 * 2), *b1 = (short*)give(256 * 2);
    short* g2 = (short*)give(256 * 2), *b2 = (short*)give(256 * 2);
    short* bproj[3];
    for (int i = 0; i < 3; ++i) bproj[i] = (short*)give(256 * 2);
    short* bfc1 = (short*)give(1024 * 2), *bfc2 = (short*)give(256 * 2);
    short* bmat = (short*)give((size_t)8 * 196 * 196 * 2);
    short* wqkvT[3], *wprojT[3];
    for (int i = 0; i < 3; ++i) wqkvT[i]  = (short*)give(768 * 256 * 2);
    for (int i = 0; i < 3; ++i) wprojT[i] = (short*)give(256 * 256 * 2);
    short* fc1T = (short*)give(1024 * 256 * 2);
    short* fc2T = (short*)give(256 * 1024 * 2);
    char*  trans = give(26u * 1024 * 1024);

    const float scale = 0.17677669529663687f;   // 1/sqrt(32), folded into Wq

    detect_kernel<<<1, 64, 0, stream>>>((const unsigned*)g1r, flag);
    PrepArgs pa;
    pa.src[0] = g1r;  pa.dst[0] = g1;  pa.n[0] = 256;
    pa.src[1] = b1r;  pa.dst[1] = b1;  pa.n[1] = 256;
    pa.src[2] = g2r;  pa.dst[2] = g2;  pa.n[2] = 256;
    pa.src[3] = b2r;  pa.dst[3] = b2;  pa.n[3] = 256;
    pa.src[4] = bprojr[0]; pa.dst[4] = bproj[0]; pa.n[4] = 256;
    pa.src[5] = bprojr[1]; pa.dst[5] = bproj[1]; pa.n[5] = 256;
    pa.src[6] = bprojr[2]; pa.dst[6] = bproj[2]; pa.n[6] = 256;
    pa.src[7] = bfc1r; pa.dst[7] = bfc1; pa.n[7] = 1024;
    pa.src[8] = bfc2r; pa.dst[8] = bfc2; pa.n[8] = 256;
    prep_kernel<<<12, 256, 0, stream>>>(pa, flag);
    biasmat_kernel<<<(8 * 196 * 196 + 255) / 256, 256, 0, stream>>>(rpbr, bmat, flag);

    for (int i = 0; i < 3; ++i) {
        transpose_kernel<<<dim3(24, 8), dim3(32, 8), 0, stream>>>(wqkv[i], wqkvT[i], 256, 768, flag, 256, scale);
        transpose_kernel<<<dim3(8, 8),  dim3(32, 8), 0, stream>>>(wproj[i], wprojT[i], 256, 256, flag, 0, 1.f);
    }
    transpose_kernel<<<dim3(32, 8), dim3(32, 8), 0, stream>>>(wfc1, fc1T, 256, 1024, flag, 0, 1.f);
    transpose_kernel<<<dim3(8, 32), dim3(32, 8), 0, stream>>>(wfc2, fc2T, 1024, 256, flag, 0, 1.f);

    ln_kernel<<<M_TOK / 4, 256, 0, stream>>>(x, g1, b1, xn, flag);

    for (int br = 0; br < 3; ++br) {
        const int N      = (br == 2) ? 196 : 784;
        const int NPAD   = (br == 2) ? 224 : 800;
        const int NCHUNK = (br == 2) ? 4 : 2;
        const int WPER   = (br == 2) ? 32 : 16;
        const int CHM    = (br == 2) ? 6272 : 12544;
        const int VSTR   = WPER * NPAD;
        for (int c = 0; c < NCHUNK; ++c) {
            int t0 = c * CHM;
            int w0 = c * WPER;
            short* qw = (short*)trans;
            short* kw = qw + (size_t)CHM * C_DIM;
            short* vw = kw + (size_t)CHM * C_DIM;   // aliased by aw after vtrans
            short* vT = vw + (size_t)CHM * C_DIM;
            short* aw = vw;
            dim3 qg(12, CHM / 64);
            if (br == 0)      gemm_qkv_kernel<0><<<qg, 256, 0, stream>>>(xn + (size_t)t0 * C_DIM, wqkvT[0], qw, kw, vw, t0, w0);
            else if (br == 1) gemm_qkv_kernel<1><<<qg, 256, 0, stream>>>(xn + (size_t)t0 * C_DIM, wqkvT[1], qw, kw, vw, t0, w0);
            else              gemm_qkv_kernel<2><<<qg, 256, 0, stream>>>(xn + (size_t)t0 * C_DIM, wqkvT[2], qw, kw, vw, t0, w0);
            vtrans_kernel<<<CHM / 28, 256, 0, stream>>>(vw, vT, N, NPAD, VSTR);
            int QT = (N + 31) >> 5;
            int tasks = WPER * NH * QT;
            attn_kernel<<<(tasks + 3) / 4, 256, 0, stream>>>(
                qw, kw, vT, (br == 2) ? bmat : nullptr, aw, WPER, N, NPAD, VSTR);
            gemm_kernel<<<dim3(4, CHM / 64), 256, 0, stream>>>(
                aw, wprojT[br], qw, 0, 256, 256, bproj[br], 0, nullptr, nullptr);
            agg_step_kernel<<<CHM / 4, 256, 0, stream>>>(
                xn, qw, facc, mst, lst, w0, N, br, br == 0 ? 1 : 0);
        }
    }

    agg_finish_kernel<<<M_TOK / 4, 256, 0, stream>>>(x, facc, lst, xn, g2, b2, flag);

    short* hbuf = (short*)trans;
    for (int q = 0; q < 4; ++q) {
        size_t ro = (size_t)q * 6272;
        gemm_kernel<<<dim3(16, 98), 256, 0, stream>>>(
            xn + ro * C_DIM, fc1T, hbuf, 0, HID_DIM, 256, bfc1, 1, nullptr, nullptr);
        gemm_kernel<<<dim3(4, 98), 256, 0, stream>>>(
            hbuf, fc2T, d_out, (int)ro, 256, HID_DIM, bfc2, 0,
            facc + ro * C_DIM, flag);
    }
}

// Round 9
// 1081.581 us; speedup vs baseline: 1.2668x; 1.1082x over previous
//
#include <hip/hip_runtime.h>
#include <hip/hip_bf16.h>

#define M_TOK   25088
#define C_DIM   256
#define NH      8
#define HID_DIM 1024
#define PSTR    40          // LDS row stride in shorts (80B: b128-aligned, ~2-way banks = free)

typedef __attribute__((ext_vector_type(8))) short short8;
typedef __attribute__((ext_vector_type(4))) short short4v;
typedef __attribute__((ext_vector_type(4))) float f32x4;

__device__ __forceinline__ short f2bf(float f) {
    return __builtin_bit_cast(short, __float2bfloat16(f));
}
__device__ __forceinline__ float bf2f(short s) {
    return __bfloat162float(__builtin_bit_cast(__hip_bfloat16, s));
}

__device__ __forceinline__ int map_t(int branch, int w, int n) {
    if (branch == 0) {
        return w * 784 + n;
    } else if (branch == 1) {
        int b = w >> 4, wc = w & 15;
        int h2 = n / 7, s = n - h2 * 7;
        return b * 12544 + h2 * 112 + wc * 7 + s;
    } else {
        int b = w >> 6, wi = w & 63;
        int wh = wi >> 3, ww = wi & 7;
        int i = n / 14, j = n - i * 14;
        return b * 12544 + (wh * 14 + i) * 112 + ww * 14 + j;
    }
}

template<int BR>
__device__ __forceinline__ void tok2win(int t, int& w, int& n) {
    if constexpr (BR == 0) {
        w = t / 784; n = t - w * 784;
    } else if constexpr (BR == 1) {
        int b = t / 12544, r = t - b * 12544;
        int h2 = r / 112, cc = r - h2 * 112;
        int wc = cc / 7, s = cc - wc * 7;
        w = b * 16 + wc; n = h2 * 7 + s;
    } else {
        int b = t / 12544, r = t - b * 12544;
        int ii = r / 112, jj = r - ii * 112;
        int wh = ii / 14, i = ii - wh * 14;
        int ww = jj / 14, j = jj - ww * 14;
        w = b * 64 + wh * 8 + ww; n = i * 14 + j;
    }
}

__global__ void detect_kernel(const unsigned* __restrict__ g1, int* flag) {
    if (threadIdx.x == 0) *flag = (g1[0] == 0x3F800000u) ? 1 : 0;
}

// One fused conversion pass for all 9 small tensors
struct PrepArgs {
    const void* src[9];
    short* dst[9];
    int n[9];
};
__global__ void prep_kernel(PrepArgs a, const int* __restrict__ flag) {
    int i = blockIdx.x * 256 + threadIdx.x;
    int fp32 = *flag;
    #pragma unroll
    for (int s = 0; s < 9; ++s) {
        if (i < a.n[s]) {
            a.dst[s][i] = fp32 ? f2bf(((const float*)a.src[s])[i])
                               : ((const short*)a.src[s])[i];
            return;
        }
        i -= a.n[s];
    }
}

// Precompute attn3 bias matrix from RAW rpb: bmat[h][n1][n2] (bf16)
__global__ void biasmat_kernel(const void* __restrict__ rpbr,
                               short* __restrict__ bmat,
                               const int* __restrict__ flag) {
    int idx = blockIdx.x * 256 + threadIdx.x;
    if (idx >= 8 * 196 * 196) return;
    int h = idx / 38416, rest = idx - h * 38416;
    int n1 = rest / 196, n2 = rest - n1 * 196;
    int i1 = n1 / 14, j1 = n1 - i1 * 14;
    int i2 = n2 / 14, j2 = n2 - i2 * 14;
    int src = ((i1 - i2 + 13) * 27 + (j1 - j2 + 13)) * 8 + h;
    bmat[idx] = *flag ? f2bf(((const float*)rpbr)[src]) : ((const short*)rpbr)[src];
}

__global__ __launch_bounds__(256) void ln_kernel(
    const void* __restrict__ x, const short* __restrict__ g,
    const short* __restrict__ b, short* __restrict__ out,
    const int* __restrict__ flag)
{
    int t = blockIdx.x * 4 + (threadIdx.x >> 6);
    int lane = threadIdx.x & 63;
    size_t base = (size_t)t * C_DIM + lane * 4;
    float v[4];
    if (*flag) {
        f32x4 hv = *(const f32x4*)((const float*)x + base);
        #pragma unroll
        for (int j = 0; j < 4; ++j) v[j] = hv[j];
    } else {
        short4v hv = *(const short4v*)((const short*)x + base);
        #pragma unroll
        for (int j = 0; j < 4; ++j) v[j] = bf2f(hv[j]);
    }
    float s = v[0] + v[1] + v[2] + v[3];
    float ss = v[0]*v[0] + v[1]*v[1] + v[2]*v[2] + v[3]*v[3];
    for (int off = 32; off; off >>= 1) {
        s  += __shfl_xor(s, off);
        ss += __shfl_xor(ss, off);
    }
    float mean = s * (1.f / 256.f);
    float var  = fmaxf(ss * (1.f / 256.f) - mean * mean, 0.f);
    float rstd = rsqrtf(var + 1e-5f);
    short4v hg = *(const short4v*)(g + lane * 4);
    short4v hb = *(const short4v*)(b + lane * 4);
    short4v o;
    #pragma unroll
    for (int j = 0; j < 4; ++j)
        o[j] = f2bf((v[j] - mean) * rstd * bf2f(hg[j]) + bf2f(hb[j]));
    *(short4v*)(out + base) = o;
}

// ---------------------------------------------------------------------------
// All 8 weight transposes in ONE dispatch. Job j covers tiles
// [pre[j], pre[j+1]); src (R x C) raw -> dst (C x R) bf16; cols < sc scaled.
// ---------------------------------------------------------------------------
struct TJobs {
    const void* src[8];
    short* dst[8];
    int R[8], C[8], sc[8], tx[8];
    int pre[9];
    float smul;
};
__global__ void transpose_all_kernel(TJobs jb, const int* __restrict__ flag)
{
    __shared__ short tile[32][33];
    int b = blockIdx.x;
    int j = 0;
    while (b >= jb.pre[j + 1]) ++j;
    int local = b - jb.pre[j];
    int tX = jb.tx[j];
    int c0 = (local % tX) * 32, r0 = (local / tX) * 32;
    const void* src = jb.src[j];
    short* dst = jb.dst[j];
    int R = jb.R[j], Cc = jb.C[j], scaleCols = jb.sc[j];
    int tx_ = threadIdx.x, ty_ = threadIdx.y;
    int fp32 = *flag;
    #pragma unroll
    for (int i = 0; i < 32; i += 8) {
        int r = r0 + ty_ + i, c = c0 + tx_;
        if (r < R && c < Cc) {
            size_t idx = (size_t)r * Cc + c;
            float v = fp32 ? ((const float*)src)[idx] : bf2f(((const short*)src)[idx]);
            if (c < scaleCols) v *= jb.smul;
            tile[ty_ + i][tx_] = f2bf(v);
        }
    }
    __syncthreads();
    #pragma unroll
    for (int i = 0; i < 32; i += 8) {
        int r = c0 + ty_ + i, c = r0 + tx_;
        if (r < Cc && c < R) dst[(size_t)r * R + c] = tile[tx_][ty_ + i];
    }
}

// Out row index = m0 + local m. oflag: null->bf16 out; else dtype per *oflag.
__global__ __launch_bounds__(256) void gemm_kernel(
    const short* __restrict__ A, const short* __restrict__ Bt,
    void* __restrict__ Out, int m0, int Nn, int Kk,
    const short* __restrict__ bias, int act, const short* __restrict__ res,
    const int* __restrict__ oflag)
{
    int lane = threadIdx.x & 63;
    int wid  = threadIdx.x >> 6;
    int waveM = wid >> 1, waveN = wid & 1;
    int mb = blockIdx.y * 64 + waveM * 32;
    int nb = blockIdx.x * 64 + waveN * 32;
    int r16 = lane & 15, q4 = lane >> 4;

    f32x4 acc[2][2];
    #pragma unroll
    for (int i = 0; i < 2; ++i)
        #pragma unroll
        for (int j = 0; j < 2; ++j)
            acc[i][j] = (f32x4){0.f, 0.f, 0.f, 0.f};

    const short* Ar0 = A  + (size_t)(mb + r16) * Kk + q4 * 8;
    const short* Ar1 = A  + (size_t)(mb + 16 + r16) * Kk + q4 * 8;
    const short* Br0 = Bt + (size_t)(nb + r16) * Kk + q4 * 8;
    const short* Br1 = Bt + (size_t)(nb + 16 + r16) * Kk + q4 * 8;

    short8 ca0 = *(const short8*)(Ar0);
    short8 ca1 = *(const short8*)(Ar1);
    short8 cb0 = *(const short8*)(Br0);
    short8 cb1 = *(const short8*)(Br1);
    #pragma unroll 4
    for (int k = 32; k <= Kk; k += 32) {
        short8 na0 = ca0, na1 = ca1, nb0 = cb0, nb1 = cb1;
        if (k < Kk) {
            na0 = *(const short8*)(Ar0 + k);
            na1 = *(const short8*)(Ar1 + k);
            nb0 = *(const short8*)(Br0 + k);
            nb1 = *(const short8*)(Br1 + k);
        }
        acc[0][0] = __builtin_amdgcn_mfma_f32_16x16x32_bf16(ca0, cb0, acc[0][0], 0, 0, 0);
        acc[0][1] = __builtin_amdgcn_mfma_f32_16x16x32_bf16(ca0, cb1, acc[0][1], 0, 0, 0);
        acc[1][0] = __builtin_amdgcn_mfma_f32_16x16x32_bf16(ca1, cb0, acc[1][0], 0, 0, 0);
        acc[1][1] = __builtin_amdgcn_mfma_f32_16x16x32_bf16(ca1, cb1, acc[1][1], 0, 0, 0);
        ca0 = na0; ca1 = na1; cb0 = nb0; cb1 = nb1;
    }

    int ofp32 = oflag ? *oflag : 0;
    #pragma unroll
    for (int mt = 0; mt < 2; ++mt) {
        #pragma unroll
        for (int nt = 0; nt < 2; ++nt) {
            int n = nb + nt * 16 + r16;
            float bval = bias ? bf2f(bias[n]) : 0.f;
            #pragma unroll
            for (int r = 0; r < 4; ++r) {
                int m = mb + mt * 16 + q4 * 4 + r;
                float v = acc[mt][nt][r] + bval;
                if (act == 1) v = 0.5f * v * (1.f + erff(v * 0.70710678118f));
                if (res) v += bf2f(res[(size_t)m * Nn + n]);
                size_t oi = (size_t)(m0 + m) * Nn + n;
                if (ofp32) ((float*)Out)[oi] = v;
                else       ((short*)Out)[oi] = f2bf(v);
            }
        }
    }
}

// QKV GEMM: q/k/v written row-major window order. q is pre-scaled via Wq.
template<int BR>
__global__ __launch_bounds__(256) void gemm_qkv_kernel(
    const short* __restrict__ A, const short* __restrict__ Bt,
    short* __restrict__ qw, short* __restrict__ kw, short* __restrict__ vw,
    int t0, int w0)
{
    constexpr int N = (BR == 2) ? 196 : 784;
    int lane = threadIdx.x & 63;
    int wid  = threadIdx.x >> 6;
    int waveM = wid >> 1, waveN = wid & 1;
    int mb = blockIdx.y * 64 + waveM * 32;
    int nb = blockIdx.x * 64 + waveN * 32;
    int r16 = lane & 15, q4 = lane >> 4;

    f32x4 acc[2][2];
    #pragma unroll
    for (int i = 0; i < 2; ++i)
        #pragma unroll
        for (int j = 0; j < 2; ++j)
            acc[i][j] = (f32x4){0.f, 0.f, 0.f, 0.f};

    const short* Ar0 = A  + (size_t)(mb + r16) * 256 + q4 * 8;
    const short* Ar1 = A  + (size_t)(mb + 16 + r16) * 256 + q4 * 8;
    const short* Br0 = Bt + (size_t)(nb + r16) * 256 + q4 * 8;
    const short* Br1 = Bt + (size_t)(nb + 16 + r16) * 256 + q4 * 8;

    short8 ca0 = *(const short8*)(Ar0);
    short8 ca1 = *(const short8*)(Ar1);
    short8 cb0 = *(const short8*)(Br0);
    short8 cb1 = *(const short8*)(Br1);
    #pragma unroll
    for (int k = 32; k <= 256; k += 32) {
        short8 na0 = ca0, na1 = ca1, nb0 = cb0, nb1 = cb1;
        if (k < 256) {
            na0 = *(const short8*)(Ar0 + k);
            na1 = *(const short8*)(Ar1 + k);
            nb0 = *(const short8*)(Br0 + k);
            nb1 = *(const short8*)(Br1 + k);
        }
        acc[0][0] = __builtin_amdgcn_mfma_f32_16x16x32_bf16(ca0, cb0, acc[0][0], 0, 0, 0);
        acc[0][1] = __builtin_amdgcn_mfma_f32_16x16x32_bf16(ca0, cb1, acc[0][1], 0, 0, 0);
        acc[1][0] = __builtin_amdgcn_mfma_f32_16x16x32_bf16(ca1, cb0, acc[1][0], 0, 0, 0);
        acc[1][1] = __builtin_amdgcn_mfma_f32_16x16x32_bf16(ca1, cb1, acc[1][1], 0, 0, 0);
        ca0 = na0; ca1 = na1; cb0 = nb0; cb1 = nb1;
    }

    #pragma unroll
    for (int mt = 0; mt < 2; ++mt) {
        #pragma unroll
        for (int r = 0; r < 4; ++r) {
            int m = mb + mt * 16 + q4 * 4 + r;
            int w, nwin;
            tok2win<BR>(t0 + m, w, nwin);
            size_t row = (size_t)((w - w0) * N + nwin) * 256;
            #pragma unroll
            for (int nt = 0; nt < 2; ++nt) {
                int n = nb + nt * 16 + r16;
                short hv = f2bf(acc[mt][nt][r]);
                if (n < 256)       qw[row + n] = hv;
                else if (n < 512)  kw[row + (n - 256)] = hv;
                else               vw[row + (n - 512)] = hv;
            }
        }
    }
}

// ---------------------------------------------------------------------------
// Flash attention v5: ONE wave per 64-thread block (best-measured occupancy),
// 32-row q-tile, padded LDS, V transposed in-LDS from row-major vw
// (no vtrans kernel, no vT global round-trip), bias LUT, prescaled q,
// deferred softmax denominator, wave_barrier only (no s_barrier drain).
// ---------------------------------------------------------------------------
__global__ __launch_bounds__(64) void attn_kernel(
    const short* __restrict__ qw, const short* __restrict__ kw,
    const short* __restrict__ vw, const short* __restrict__ bmat,
    short* __restrict__ aw, int N)
{
    __shared__ alignas(16) short pbuf[32 * PSTR];
    __shared__ alignas(16) short vtile[32 * PSTR];
    int lane = threadIdx.x;
    int QT = (N + 31) >> 5;
    int task = blockIdx.x;
    int qt = task % QT;
    int t2 = task / QT;
    int h = t2 & 7;
    int w = t2 >> 3;
    int r16 = lane & 15, q4 = lane >> 4;
    int wbase = w * N;

    int qr0 = qt * 32 + r16;      if (qr0 >= N) qr0 = N - 1;
    int qr1 = qt * 32 + 16 + r16; if (qr1 >= N) qr1 = N - 1;
    short8 aq0 = *(const short8*)(qw + (size_t)(wbase + qr0) * 256 + h * 32 + q4 * 8);
    short8 aq1 = *(const short8*)(qw + (size_t)(wbase + qr1) * 256 + h * 32 + q4 * 8);

    f32x4 o00 = {0.f,0.f,0.f,0.f}, o01 = o00, o10 = o00, o11 = o00;
    float ps0[4] = {0.f,0.f,0.f,0.f}, ps1[4] = {0.f,0.f,0.f,0.f};
    const short* bh = bmat ? bmat + (size_t)h * 38416 : nullptr;
    const short* krow = kw + (size_t)wbase * 256 + h * 32 + q4 * 8;
    f32x4 zero = {0.f,0.f,0.f,0.f};

    int vrow  = lane >> 1;          // 0..31: key row within chunk
    int vhalf = (lane & 1) * 16;    // channel half

    int nch = (N + 31) >> 5;
    for (int kb = 0; kb < nch; ++kb) {
        int kbase = kb * 32;
        int kr0 = kbase + r16;      int kr0c = kr0 < N ? kr0 : N - 1;
        int kr1 = kbase + 16 + r16; int kr1c = kr1 < N ? kr1 : N - 1;
        short8 bk0 = *(const short8*)(krow + (size_t)kr0c * 256);
        short8 bk1 = *(const short8*)(krow + (size_t)kr1c * 256);

        // stage V chunk into LDS transposed: vtile[ch][key]
        int vr = kbase + vrow; if (vr >= N) vr = N - 1;
        const short* vsrc = vw + (size_t)(wbase + vr) * 256 + h * 32 + vhalf;
        short8 va = *(const short8*)(vsrc);
        short8 vb = *(const short8*)(vsrc + 8);
        #pragma unroll
        for (int j = 0; j < 8; ++j) {
            vtile[(vhalf + j) * PSTR + vrow]     = va[j];
            vtile[(vhalf + 8 + j) * PSTR + vrow] = vb[j];
        }

        f32x4 s00 = __builtin_amdgcn_mfma_f32_16x16x32_bf16(aq0, bk0, zero, 0, 0, 0);
        f32x4 s01 = __builtin_amdgcn_mfma_f32_16x16x32_bf16(aq0, bk1, zero, 0, 0, 0);
        f32x4 s10 = __builtin_amdgcn_mfma_f32_16x16x32_bf16(aq1, bk0, zero, 0, 0, 0);
        f32x4 s11 = __builtin_amdgcn_mfma_f32_16x16x32_bf16(aq1, bk1, zero, 0, 0, 0);

        if (bh) {
            #pragma unroll
            for (int r = 0; r < 4; ++r) {
                int n1a = qt * 32 + q4 * 4 + r;      if (n1a >= N) n1a = N - 1;
                int n1b = qt * 32 + 16 + q4 * 4 + r; if (n1b >= N) n1b = N - 1;
                const short* bpa = bh + n1a * 196;
                const short* bpb = bh + n1b * 196;
                if (kr0 < N) { s00[r] += bf2f(bpa[kr0]); s10[r] += bf2f(bpb[kr0]); }
                if (kr1 < N) { s01[r] += bf2f(bpa[kr1]); s11[r] += bf2f(bpb[kr1]); }
            }
        }
        if (kbase + 32 > N) {
            #pragma unroll
            for (int r = 0; r < 4; ++r) {
                if (kr0 >= N) { s00[r] = -30000.f; s10[r] = -30000.f; }
                if (kr1 >= N) { s01[r] = -30000.f; s11[r] = -30000.f; }
            }
        }

        #pragma unroll
        for (int r = 0; r < 4; ++r) {
            int ra = (q4 * 4 + r) * PSTR, rb = (16 + q4 * 4 + r) * PSTR;
            float e;
            e = __expf(s00[r]); ps0[r] += e; pbuf[ra + r16]      = f2bf(e);
            e = __expf(s01[r]); ps0[r] += e; pbuf[ra + 16 + r16] = f2bf(e);
            e = __expf(s10[r]); ps1[r] += e; pbuf[rb + r16]      = f2bf(e);
            e = __expf(s11[r]); ps1[r] += e; pbuf[rb + 16 + r16] = f2bf(e);
        }
        __builtin_amdgcn_wave_barrier();   // LDS writes before reads
        short8 ap0 = *(const short8*)(pbuf + r16 * PSTR + q4 * 8);
        short8 ap1 = *(const short8*)(pbuf + (16 + r16) * PSTR + q4 * 8);
        short8 bv0 = *(const short8*)(vtile + r16 * PSTR + q4 * 8);
        short8 bv1 = *(const short8*)(vtile + (16 + r16) * PSTR + q4 * 8);
        __builtin_amdgcn_wave_barrier();   // reads before next-iter writes
        o00 = __builtin_amdgcn_mfma_f32_16x16x32_bf16(ap0, bv0, o00, 0, 0, 0);
        o01 = __builtin_amdgcn_mfma_f32_16x16x32_bf16(ap0, bv1, o01, 0, 0, 0);
        o10 = __builtin_amdgcn_mfma_f32_16x16x32_bf16(ap1, bv0, o10, 0, 0, 0);
        o11 = __builtin_amdgcn_mfma_f32_16x16x32_bf16(ap1, bv1, o11, 0, 0, 0);
    }

    #pragma unroll
    for (int msk = 1; msk < 16; msk <<= 1)
        #pragma unroll
        for (int r = 0; r < 4; ++r) {
            ps0[r] += __shfl_xor(ps0[r], msk);
            ps1[r] += __shfl_xor(ps1[r], msk);
        }

    #pragma unroll
    for (int r = 0; r < 4; ++r) {
        int n1 = qt * 32 + q4 * 4 + r;
        if (n1 < N) {
            float inv = 1.f / fmaxf(ps0[r], 1e-20f);
            size_t row = (size_t)(wbase + n1) * 256;
            aw[row + h * 32 + r16]      = f2bf(o00[r] * inv);
            aw[row + h * 32 + 16 + r16] = f2bf(o01[r] * inv);
        }
        int n2 = qt * 32 + 16 + q4 * 4 + r;
        if (n2 < N) {
            float inv = 1.f / fmaxf(ps1[r], 1e-20f);
            size_t row = (size_t)(wbase + n2) * 256;
            aw[row + h * 32 + r16]      = f2bf(o10[r] * inv);
            aw[row + h * 32 + 16 + r16] = f2bf(o11[r] * inv);
        }
    }
}

__global__ __launch_bounds__(256) void agg_step_kernel(
    const short* __restrict__ xn, const short* __restrict__ pw,
    short* __restrict__ facc, float* __restrict__ mst, float* __restrict__ lst,
    int w0, int N, int branch, int first)
{
    int tp = blockIdx.x * 4 + (threadIdx.x >> 6);
    int lane = threadIdx.x & 63;
    int wl = tp / N, n = tp - wl * N;
    int t = map_t(branch, w0 + wl, n);
    size_t pbase = (size_t)tp * C_DIM + lane * 4;
    size_t tbase = (size_t)t * C_DIM + lane * 4;
    short4v hp = *(const short4v*)(pw + pbase);
    short4v hn = *(const short4v*)(xn + tbase);
    float pv[4], nv[4];
    #pragma unroll
    for (int j = 0; j < 4; ++j) { pv[j] = bf2f(hp[j]); nv[j] = bf2f(hn[j]); }
    float d = pv[0]*nv[0] + pv[1]*nv[1] + pv[2]*nv[2] + pv[3]*nv[3];
    for (int off = 32; off; off >>= 1) d += __shfl_xor(d, off);
    d *= 0.0625f;

    float mo, lo;
    if (first) { mo = -30000.f; lo = 0.f; }
    else       { mo = mst[t];   lo = lst[t]; }
    float mn = fmaxf(mo, d);
    float a  = __expf(mo - mn);
    float e  = __expf(d - mn);
    short4v fo;
    if (first) {
        #pragma unroll
        for (int j = 0; j < 4; ++j) fo[j] = f2bf(e * pv[j]);
    } else {
        short4v hf = *(const short4v*)(facc + tbase);
        #pragma unroll
        for (int j = 0; j < 4; ++j) fo[j] = f2bf(bf2f(hf[j]) * a + e * pv[j]);
    }
    *(short4v*)(facc + tbase) = fo;
    if (lane == 0) { mst[t] = mn; lst[t] = lo * a + e; }
}

__global__ __launch_bounds__(256) void agg_finish_kernel(
    const void* __restrict__ x, short* __restrict__ facc,
    const float* __restrict__ lst, short* __restrict__ xn,
    const short* __restrict__ g2, const short* __restrict__ b2,
    const int* __restrict__ flag)
{
    int t = blockIdx.x * 4 + (threadIdx.x >> 6);
    int lane = threadIdx.x & 63;
    size_t base = (size_t)t * C_DIM + lane * 4;
    float vx[4];
    if (*flag) {
        f32x4 hv = *(const f32x4*)((const float*)x + base);
        #pragma unroll
        for (int j = 0; j < 4; ++j) vx[j] = hv[j];
    } else {
        short4v hv = *(const short4v*)((const short*)x + base);
        #pragma unroll
        for (int j = 0; j < 4; ++j) vx[j] = bf2f(hv[j]);
    }
    short4v hf = *(const short4v*)(facc + base);
    float linv = 1.f / fmaxf(lst[t], 1e-20f);
    float vy[4];
    #pragma unroll
    for (int j = 0; j < 4; ++j) vy[j] = vx[j] + bf2f(hf[j]) * linv;
    float s = 0.f, ss = 0.f;
    #pragma unroll
    for (int j = 0; j < 4; ++j) { s += vy[j]; ss += vy[j] * vy[j]; }
    for (int off = 32; off; off >>= 1) {
        s  += __shfl_xor(s, off);
        ss += __shfl_xor(ss, off);
    }
    float mean = s * (1.f / 256.f);
    float var  = fmaxf(ss * (1.f / 256.f) - mean * mean, 0.f);
    float rstd = rsqrtf(var + 1e-5f);
    short4v hg = *(const short4v*)(g2 + lane * 4);
    short4v hb = *(const short4v*)(b2 + lane * 4);
    short4v oy, on;
    #pragma unroll
    for (int j = 0; j < 4; ++j) {
        oy[j] = f2bf(vy[j]);
        on[j] = f2bf((vy[j] - mean) * rstd * bf2f(hg[j]) + bf2f(hb[j]));
    }
    *(short4v*)(facc + base) = oy;
    *(short4v*)(xn   + base) = on;
}

extern "C" void kernel_launch(void* const* d_in, const int* in_sizes, int n_in,
                              void* d_out, int out_size, void* d_ws, size_t ws_size,
                              hipStream_t stream)
{
    const void* x   = d_in[0];
    const void* g1r = d_in[1];
    const void* b1r = d_in[2];
    const void* g2r = d_in[3];
    const void* b2r = d_in[4];
    const void* wqkv[3]   = {d_in[5], d_in[8],  d_in[11]};
    const void* wproj[3]  = {d_in[6], d_in[9],  d_in[12]};
    const void* bprojr[3] = {d_in[7], d_in[10], d_in[13]};
    const void* rpbr  = d_in[14];
    const void* wfc1  = d_in[15];
    const void* bfc1r = d_in[16];
    const void* wfc2  = d_in[17];
    const void* bfc2r = d_in[18];

    char* ws = (char*)d_ws;
    size_t off = 0;
    auto give = [&](size_t bytes) -> char* {
        char* p = ws + off;
        off += (bytes + 255) & ~(size_t)255;
        return p;
    };
    int*   flag = (int*)give(256);
    short* xn   = (short*)give((size_t)M_TOK * C_DIM * 2);
    short* facc = (short*)give((size_t)M_TOK * C_DIM * 2);
    float* mst  = (float*)give((size_t)M_TOK * 4);
    float* lst  = (float*)give((size_t)M_TOK * 4);
    short* g1 = (short*)give(256 * 2), *b1 = (short*)give(256 * 2);
    short* g2 = (short*)give(256 * 2), *b2 = (short*)give(256 * 2);
    short* bproj[3];
    for (int i = 0; i < 3; ++i) bproj[i] = (short*)give(256 * 2);
    short* bfc1 = (short*)give(1024 * 2), *bfc2 = (short*)give(256 * 2);
    short* bmat = (short*)give((size_t)8 * 196 * 196 * 2);
    short* wqkvT[3], *wprojT[3];
    for (int i = 0; i < 3; ++i) wqkvT[i]  = (short*)give(768 * 256 * 2);
    for (int i = 0; i < 3; ++i) wprojT[i] = (short*)give(256 * 256 * 2);
    short* fc1T = (short*)give(1024 * 256 * 2);
    short* fc2T = (short*)give(256 * 1024 * 2);
    char*  trans = give(26u * 1024 * 1024);

    const float scale = 0.17677669529663687f;   // 1/sqrt(32), folded into Wq

    detect_kernel<<<1, 64, 0, stream>>>((const unsigned*)g1r, flag);
    PrepArgs pa;
    pa.src[0] = g1r;  pa.dst[0] = g1;  pa.n[0] = 256;
    pa.src[1] = b1r;  pa.dst[1] = b1;  pa.n[1] = 256;
    pa.src[2] = g2r;  pa.dst[2] = g2;  pa.n[2] = 256;
    pa.src[3] = b2r;  pa.dst[3] = b2;  pa.n[3] = 256;
    pa.src[4] = bprojr[0]; pa.dst[4] = bproj[0]; pa.n[4] = 256;
    pa.src[5] = bprojr[1]; pa.dst[5] = bproj[1]; pa.n[5] = 256;
    pa.src[6] = bprojr[2]; pa.dst[6] = bproj[2]; pa.n[6] = 256;
    pa.src[7] = bfc1r; pa.dst[7] = bfc1; pa.n[7] = 1024;
    pa.src[8] = bfc2r; pa.dst[8] = bfc2; pa.n[8] = 256;
    prep_kernel<<<12, 256, 0, stream>>>(pa, flag);
    biasmat_kernel<<<(8 * 196 * 196 + 255) / 256, 256, 0, stream>>>(rpbr, bmat, flag);

    TJobs tj;
    tj.smul = scale;
    int pre = 0;
    for (int i = 0; i < 3; ++i) {   // wqkv: 256x768, scale q cols
        tj.src[i] = wqkv[i]; tj.dst[i] = wqkvT[i];
        tj.R[i] = 256; tj.C[i] = 768; tj.sc[i] = 256; tj.tx[i] = 24;
        tj.pre[i] = pre; pre += 24 * 8;
    }
    for (int i = 0; i < 3; ++i) {   // wproj: 256x256
        tj.src[3 + i] = wproj[i]; tj.dst[3 + i] = wprojT[i];
        tj.R[3 + i] = 256; tj.C[3 + i] = 256; tj.sc[3 + i] = 0; tj.tx[3 + i] = 8;
        tj.pre[3 + i] = pre; pre += 8 * 8;
    }
    tj.src[6] = wfc1; tj.dst[6] = fc1T;
    tj.R[6] = 256; tj.C[6] = 1024; tj.sc[6] = 0; tj.tx[6] = 32;
    tj.pre[6] = pre; pre += 32 * 8;
    tj.src[7] = wfc2; tj.dst[7] = fc2T;
    tj.R[7] = 1024; tj.C[7] = 256; tj.sc[7] = 0; tj.tx[7] = 8;
    tj.pre[7] = pre; pre += 8 * 32;
    tj.pre[8] = pre;
    transpose_all_kernel<<<pre, dim3(32, 8), 0, stream>>>(tj, flag);

    ln_kernel<<<M_TOK / 4, 256, 0, stream>>>(x, g1, b1, xn, flag);

    for (int br = 0; br < 3; ++br) {
        const int N      = (br == 2) ? 196 : 784;
        const int NCHUNK = (br == 2) ? 4 : 2;
        const int WPER   = (br == 2) ? 32 : 16;
        const int CHM    = (br == 2) ? 6272 : 12544;
        for (int c = 0; c < NCHUNK; ++c) {
            int t0 = c * CHM;
            int w0 = c * WPER;
            short* qw = (short*)trans;
            short* kw = qw + (size_t)CHM * C_DIM;
            short* vw = kw + (size_t)CHM * C_DIM;
            short* aw = vw + (size_t)CHM * C_DIM;
            dim3 qg(12, CHM / 64);
            if (br == 0)      gemm_qkv_kernel<0><<<qg, 256, 0, stream>>>(xn + (size_t)t0 * C_DIM, wqkvT[0], qw, kw, vw, t0, w0);
            else if (br == 1) gemm_qkv_kernel<1><<<qg, 256, 0, stream>>>(xn + (size_t)t0 * C_DIM, wqkvT[1], qw, kw, vw, t0, w0);
            else              gemm_qkv_kernel<2><<<qg, 256, 0, stream>>>(xn + (size_t)t0 * C_DIM, wqkvT[2], qw, kw, vw, t0, w0);
            int QT = (N + 31) >> 5;
            int tasks = WPER * NH * QT;
            attn_kernel<<<tasks, 64, 0, stream>>>(
                qw, kw, vw, (br == 2) ? bmat : nullptr, aw, N);
            gemm_kernel<<<dim3(4, CHM / 64), 256, 0, stream>>>(
                aw, wprojT[br], qw, 0, 256, 256, bproj[br], 0, nullptr, nullptr);
            agg_step_kernel<<<CHM / 4, 256, 0, stream>>>(
                xn, qw, facc, mst, lst, w0, N, br, br == 0 ? 1 : 0);
        }
    }

    agg_finish_kernel<<<M_TOK / 4, 256, 0, stream>>>(x, facc, lst, xn, g2, b2, flag);

    short* hbuf = (short*)trans;
    for (int q = 0; q < 4; ++q) {
        size_t ro = (size_t)q * 6272;
        gemm_kernel<<<dim3(16, 98), 256, 0, stream>>>(
            xn + ro * C_DIM, fc1T, hbuf, 0, HID_DIM, 256, bfc1, 1, nullptr, nullptr);
        gemm_kernel<<<dim3(4, 98), 256, 0, stream>>>(
            hbuf, fc2T, d_out, (int)ro, 256, HID_DIM, bfc2, 0,
            facc + ro * C_DIM, flag);
    }
}

// Round 10
// 871.231 us; speedup vs baseline: 1.5726x; 1.2414x over previous
//
#include <hip/hip_runtime.h>
#include <hip/hip_bf16.h>

#define M_TOK   25088
#define C_DIM   256
#define NH      8
#define HID_DIM 1024
#define PSTR    40     // attn LDS row stride (shorts)
#define ASTR    40     // gemm LDS row stride (shorts): 80B, b128-aligned, padded

typedef __attribute__((ext_vector_type(8))) short short8;
typedef __attribute__((ext_vector_type(4))) short short4v;
typedef __attribute__((ext_vector_type(4))) float f32x4;

__device__ __forceinline__ short f2bf(float f) {
    return __builtin_bit_cast(short, __float2bfloat16(f));
}
__device__ __forceinline__ float bf2f(short s) {
    return __bfloat162float(__builtin_bit_cast(__hip_bfloat16, s));
}

__device__ __forceinline__ int map_t(int branch, int w, int n) {
    if (branch == 0) {
        return w * 784 + n;
    } else if (branch == 1) {
        int b = w >> 4, wc = w & 15;
        int h2 = n / 7, s = n - h2 * 7;
        return b * 12544 + h2 * 112 + wc * 7 + s;
    } else {
        int b = w >> 6, wi = w & 63;
        int wh = wi >> 3, ww = wi & 7;
        int i = n / 14, j = n - i * 14;
        return b * 12544 + (wh * 14 + i) * 112 + ww * 14 + j;
    }
}

template<int BR>
__device__ __forceinline__ void tok2win(int t, int& w, int& n) {
    if constexpr (BR == 0) {
        w = t / 784; n = t - w * 784;
    } else if constexpr (BR == 1) {
        int b = t / 12544, r = t - b * 12544;
        int h2 = r / 112, cc = r - h2 * 112;
        int wc = cc / 7, s = cc - wc * 7;
        w = b * 16 + wc; n = h2 * 7 + s;
    } else {
        int b = t / 12544, r = t - b * 12544;
        int ii = r / 112, jj = r - ii * 112;
        int wh = ii / 14, i = ii - wh * 14;
        int ww = jj / 14, j = jj - ww * 14;
        w = b * 64 + wh * 8 + ww; n = i * 14 + j;
    }
}

__global__ void detect_kernel(const unsigned* __restrict__ g1, int* flag) {
    if (threadIdx.x == 0) *flag = (g1[0] == 0x3F800000u) ? 1 : 0;
}

struct PrepArgs {
    const void* src[9];
    short* dst[9];
    int n[9];
};
__global__ void prep_kernel(PrepArgs a, const int* __restrict__ flag) {
    int i = blockIdx.x * 256 + threadIdx.x;
    int fp32 = *flag;
    #pragma unroll
    for (int s = 0; s < 9; ++s) {
        if (i < a.n[s]) {
            a.dst[s][i] = fp32 ? f2bf(((const float*)a.src[s])[i])
                               : ((const short*)a.src[s])[i];
            return;
        }
        i -= a.n[s];
    }
}

__global__ void biasmat_kernel(const void* __restrict__ rpbr,
                               short* __restrict__ bmat,
                               const int* __restrict__ flag) {
    int idx = blockIdx.x * 256 + threadIdx.x;
    if (idx >= 8 * 196 * 196) return;
    int h = idx / 38416, rest = idx - h * 38416;
    int n1 = rest / 196, n2 = rest - n1 * 196;
    int i1 = n1 / 14, j1 = n1 - i1 * 14;
    int i2 = n2 / 14, j2 = n2 - i2 * 14;
    int src = ((i1 - i2 + 13) * 27 + (j1 - j2 + 13)) * 8 + h;
    bmat[idx] = *flag ? f2bf(((const float*)rpbr)[src]) : ((const short*)rpbr)[src];
}

__global__ __launch_bounds__(256) void ln_kernel(
    const void* __restrict__ x, const short* __restrict__ g,
    const short* __restrict__ b, short* __restrict__ out,
    const int* __restrict__ flag)
{
    int t = blockIdx.x * 4 + (threadIdx.x >> 6);
    int lane = threadIdx.x & 63;
    size_t base = (size_t)t * C_DIM + lane * 4;
    float v[4];
    if (*flag) {
        f32x4 hv = *(const f32x4*)((const float*)x + base);
        #pragma unroll
        for (int j = 0; j < 4; ++j) v[j] = hv[j];
    } else {
        short4v hv = *(const short4v*)((const short*)x + base);
        #pragma unroll
        for (int j = 0; j < 4; ++j) v[j] = bf2f(hv[j]);
    }
    float s = v[0] + v[1] + v[2] + v[3];
    float ss = v[0]*v[0] + v[1]*v[1] + v[2]*v[2] + v[3]*v[3];
    for (int off = 32; off; off >>= 1) {
        s  += __shfl_xor(s, off);
        ss += __shfl_xor(ss, off);
    }
    float mean = s * (1.f / 256.f);
    float var  = fmaxf(ss * (1.f / 256.f) - mean * mean, 0.f);
    float rstd = rsqrtf(var + 1e-5f);
    short4v hg = *(const short4v*)(g + lane * 4);
    short4v hb = *(const short4v*)(b + lane * 4);
    short4v o;
    #pragma unroll
    for (int j = 0; j < 4; ++j)
        o[j] = f2bf((v[j] - mean) * rstd * bf2f(hg[j]) + bf2f(hb[j]));
    *(short4v*)(out + base) = o;
}

// All 8 weight transposes in one dispatch.
struct TJobs {
    const void* src[8];
    short* dst[8];
    int R[8], C[8], sc[8], tx[8];
    int pre[9];
    float smul;
};
__global__ void transpose_all_kernel(TJobs jb, const int* __restrict__ flag)
{
    __shared__ short tile[32][33];
    int b = blockIdx.x;
    int j = 0;
    while (b >= jb.pre[j + 1]) ++j;
    int local = b - jb.pre[j];
    int tX = jb.tx[j];
    int c0 = (local % tX) * 32, r0 = (local / tX) * 32;
    const void* src = jb.src[j];
    short* dst = jb.dst[j];
    int R = jb.R[j], Cc = jb.C[j], scaleCols = jb.sc[j];
    int tx_ = threadIdx.x, ty_ = threadIdx.y;
    int fp32 = *flag;
    #pragma unroll
    for (int i = 0; i < 32; i += 8) {
        int r = r0 + ty_ + i, c = c0 + tx_;
        if (r < R && c < Cc) {
            size_t idx = (size_t)r * Cc + c;
            float v = fp32 ? ((const float*)src)[idx] : bf2f(((const short*)src)[idx]);
            if (c < scaleCols) v *= jb.smul;
            tile[ty_ + i][tx_] = f2bf(v);
        }
    }
    __syncthreads();
    #pragma unroll
    for (int i = 0; i < 32; i += 8) {
        int r = c0 + ty_ + i, c = r0 + tx_;
        if (r < Cc && c < R) dst[(size_t)r * R + c] = tile[tx_][ty_ + i];
    }
}

// ---------------------------------------------------------------------------
// 128x128-tile LDS-staged GEMM (m93 structure): 4 waves (2x2) of 64x64,
// BK=32, padded LDS, 16 MFMA/wave/K-step. Out row = m0 + m.
// ---------------------------------------------------------------------------
__global__ __launch_bounds__(256) void gemm128_kernel(
    const short* __restrict__ A, const short* __restrict__ Bt,
    void* __restrict__ Out, int m0, int Nn, int Kk,
    const short* __restrict__ bias, int act, const short* __restrict__ res,
    const int* __restrict__ oflag)
{
    __shared__ alignas(16) short As[128 * ASTR];
    __shared__ alignas(16) short Bs[128 * ASTR];
    int tid = threadIdx.x;
    int lane = tid & 63, wid = tid >> 6;
    int wrow = (wid >> 1) * 64, wcol = (wid & 1) * 64;
    int r16 = lane & 15, q4 = lane >> 4;
    int mb = blockIdx.y * 128, nb = blockIdx.x * 128;

    int srow = tid >> 1, sh = (tid & 1) * 16;
    const short* Ag = A  + (size_t)(mb + srow) * Kk + sh;
    const short* Bg = Bt + (size_t)(nb + srow) * Kk + sh;
    short* Al = As + srow * ASTR + sh;
    short* Bl = Bs + srow * ASTR + sh;

    f32x4 acc[4][4];
    #pragma unroll
    for (int i = 0; i < 4; ++i)
        #pragma unroll
        for (int j = 0; j < 4; ++j)
            acc[i][j] = (f32x4){0.f, 0.f, 0.f, 0.f};

    for (int k0 = 0; k0 < Kk; k0 += 32) {
        short8 a0 = *(const short8*)(Ag + k0);
        short8 a1 = *(const short8*)(Ag + k0 + 8);
        short8 b0 = *(const short8*)(Bg + k0);
        short8 b1 = *(const short8*)(Bg + k0 + 8);
        *(short8*)(Al)     = a0;
        *(short8*)(Al + 8) = a1;
        *(short8*)(Bl)     = b0;
        *(short8*)(Bl + 8) = b1;
        __syncthreads();
        short8 af[4], bf[4];
        #pragma unroll
        for (int mi = 0; mi < 4; ++mi)
            af[mi] = *(const short8*)(As + (wrow + mi * 16 + r16) * ASTR + q4 * 8);
        #pragma unroll
        for (int ni = 0; ni < 4; ++ni)
            bf[ni] = *(const short8*)(Bs + (wcol + ni * 16 + r16) * ASTR + q4 * 8);
        #pragma unroll
        for (int mi = 0; mi < 4; ++mi)
            #pragma unroll
            for (int ni = 0; ni < 4; ++ni)
                acc[mi][ni] = __builtin_amdgcn_mfma_f32_16x16x32_bf16(af[mi], bf[ni], acc[mi][ni], 0, 0, 0);
        __syncthreads();
    }

    int ofp32 = oflag ? *oflag : 0;
    #pragma unroll
    for (int mi = 0; mi < 4; ++mi) {
        #pragma unroll
        for (int ni = 0; ni < 4; ++ni) {
            int n = nb + wcol + ni * 16 + r16;
            float bval = bias ? bf2f(bias[n]) : 0.f;
            #pragma unroll
            for (int r = 0; r < 4; ++r) {
                int m = mb + wrow + mi * 16 + q4 * 4 + r;
                float v = acc[mi][ni][r] + bval;
                if (act == 1) v = 0.5f * v * (1.f + erff(v * 0.70710678118f));
                if (res) v += bf2f(res[(size_t)m * Nn + n]);
                size_t oi = (size_t)(m0 + m) * Nn + n;
                if (ofp32) ((float*)Out)[oi] = v;
                else       ((short*)Out)[oi] = f2bf(v);
            }
        }
    }
}

// Same 128-tile GEMM with fused q/k/v window-scatter epilogue (q pre-scaled).
template<int BR>
__global__ __launch_bounds__(256) void gemm_qkv128_kernel(
    const short* __restrict__ A, const short* __restrict__ Bt,
    short* __restrict__ qw, short* __restrict__ kw, short* __restrict__ vw,
    int t0, int w0)
{
    constexpr int N = (BR == 2) ? 196 : 784;
    __shared__ alignas(16) short As[128 * ASTR];
    __shared__ alignas(16) short Bs[128 * ASTR];
    int tid = threadIdx.x;
    int lane = tid & 63, wid = tid >> 6;
    int wrow = (wid >> 1) * 64, wcol = (wid & 1) * 64;
    int r16 = lane & 15, q4 = lane >> 4;
    int mb = blockIdx.y * 128, nb = blockIdx.x * 128;

    int srow = tid >> 1, sh = (tid & 1) * 16;
    const short* Ag = A  + (size_t)(mb + srow) * 256 + sh;
    const short* Bg = Bt + (size_t)(nb + srow) * 256 + sh;
    short* Al = As + srow * ASTR + sh;
    short* Bl = Bs + srow * ASTR + sh;

    f32x4 acc[4][4];
    #pragma unroll
    for (int i = 0; i < 4; ++i)
        #pragma unroll
        for (int j = 0; j < 4; ++j)
            acc[i][j] = (f32x4){0.f, 0.f, 0.f, 0.f};

    #pragma unroll 2
    for (int k0 = 0; k0 < 256; k0 += 32) {
        short8 a0 = *(const short8*)(Ag + k0);
        short8 a1 = *(const short8*)(Ag + k0 + 8);
        short8 b0 = *(const short8*)(Bg + k0);
        short8 b1 = *(const short8*)(Bg + k0 + 8);
        *(short8*)(Al)     = a0;
        *(short8*)(Al + 8) = a1;
        *(short8*)(Bl)     = b0;
        *(short8*)(Bl + 8) = b1;
        __syncthreads();
        short8 af[4], bf[4];
        #pragma unroll
        for (int mi = 0; mi < 4; ++mi)
            af[mi] = *(const short8*)(As + (wrow + mi * 16 + r16) * ASTR + q4 * 8);
        #pragma unroll
        for (int ni = 0; ni < 4; ++ni)
            bf[ni] = *(const short8*)(Bs + (wcol + ni * 16 + r16) * ASTR + q4 * 8);
        #pragma unroll
        for (int mi = 0; mi < 4; ++mi)
            #pragma unroll
            for (int ni = 0; ni < 4; ++ni)
                acc[mi][ni] = __builtin_amdgcn_mfma_f32_16x16x32_bf16(af[mi], bf[ni], acc[mi][ni], 0, 0, 0);
        __syncthreads();
    }

    #pragma unroll
    for (int mi = 0; mi < 4; ++mi) {
        #pragma unroll
        for (int r = 0; r < 4; ++r) {
            int m = mb + wrow + mi * 16 + q4 * 4 + r;
            int w, nwin;
            tok2win<BR>(t0 + m, w, nwin);
            size_t row = (size_t)((w - w0) * N + nwin) * 256;
            #pragma unroll
            for (int ni = 0; ni < 4; ++ni) {
                int n = nb + wcol + ni * 16 + r16;
                short hv = f2bf(acc[mi][ni][r]);
                if (n < 256)       qw[row + n] = hv;
                else if (n < 512)  kw[row + (n - 256)] = hv;
                else               vw[row + (n - 512)] = hv;
            }
        }
    }
}

// ---------------------------------------------------------------------------
// Flash attention: 1 wave / 64-thread block, 32-row q-tile, XOR-swizzled
// pbuf (conflict-free writes), in-LDS V transpose, bias LUT, prescaled q,
// wave_barrier only.
// P element (m,k) stored at m*PSTR + ((k>>3 ^ (m>>2&3))&3)*8 + (k&7).
// ---------------------------------------------------------------------------
__global__ __launch_bounds__(64) void attn_kernel(
    const short* __restrict__ qw, const short* __restrict__ kw,
    const short* __restrict__ vw, const short* __restrict__ bmat,
    short* __restrict__ aw, int N)
{
    __shared__ alignas(16) short pbuf[32 * PSTR];
    __shared__ alignas(16) short vtile[32 * PSTR];
    int lane = threadIdx.x;
    int QT = (N + 31) >> 5;
    int task = blockIdx.x;
    int qt = task % QT;
    int t2 = task / QT;
    int h = t2 & 7;
    int w = t2 >> 3;
    int r16 = lane & 15, q4 = lane >> 4;
    int wbase = w * N;

    int qr0 = qt * 32 + r16;      if (qr0 >= N) qr0 = N - 1;
    int qr1 = qt * 32 + 16 + r16; if (qr1 >= N) qr1 = N - 1;
    short8 aq0 = *(const short8*)(qw + (size_t)(wbase + qr0) * 256 + h * 32 + q4 * 8);
    short8 aq1 = *(const short8*)(qw + (size_t)(wbase + qr1) * 256 + h * 32 + q4 * 8);

    f32x4 o00 = {0.f,0.f,0.f,0.f}, o01 = o00, o10 = o00, o11 = o00;
    float ps0[4] = {0.f,0.f,0.f,0.f}, ps1[4] = {0.f,0.f,0.f,0.f};
    const short* bh = bmat ? bmat + (size_t)h * 38416 : nullptr;
    const short* krow = kw + (size_t)wbase * 256 + h * 32 + q4 * 8;
    f32x4 zero = {0.f,0.f,0.f,0.f};

    int vrow  = lane >> 1;
    int vhalf = (lane & 1) * 16;
    // swizzled pbuf column offsets for this lane
    int c0 = (((r16 >> 3) ^ q4) & 3) * 8 + (r16 & 7);
    int c1 = (((2 + (r16 >> 3)) ^ q4) & 3) * 8 + (r16 & 7);
    int rs = (r16 >> 2) & 3;
    int rdoff = ((q4 ^ rs) & 3) * 8;

    int nch = (N + 31) >> 5;
    for (int kb = 0; kb < nch; ++kb) {
        int kbase = kb * 32;
        int kr0 = kbase + r16;      int kr0c = kr0 < N ? kr0 : N - 1;
        int kr1 = kbase + 16 + r16; int kr1c = kr1 < N ? kr1 : N - 1;
        short8 bk0 = *(const short8*)(krow + (size_t)kr0c * 256);
        short8 bk1 = *(const short8*)(krow + (size_t)kr1c * 256);

        int vr = kbase + vrow; if (vr >= N) vr = N - 1;
        const short* vsrc = vw + (size_t)(wbase + vr) * 256 + h * 32 + vhalf;
        short8 va = *(const short8*)(vsrc);
        short8 vb = *(const short8*)(vsrc + 8);
        #pragma unroll
        for (int j = 0; j < 8; ++j) {
            vtile[(vhalf + j) * PSTR + vrow]     = va[j];
            vtile[(vhalf + 8 + j) * PSTR + vrow] = vb[j];
        }

        f32x4 s00 = __builtin_amdgcn_mfma_f32_16x16x32_bf16(aq0, bk0, zero, 0, 0, 0);
        f32x4 s01 = __builtin_amdgcn_mfma_f32_16x16x32_bf16(aq0, bk1, zero, 0, 0, 0);
        f32x4 s10 = __builtin_amdgcn_mfma_f32_16x16x32_bf16(aq1, bk0, zero, 0, 0, 0);
        f32x4 s11 = __builtin_amdgcn_mfma_f32_16x16x32_bf16(aq1, bk1, zero, 0, 0, 0);

        if (bh) {
            #pragma unroll
            for (int r = 0; r < 4; ++r) {
                int n1a = qt * 32 + q4 * 4 + r;      if (n1a >= N) n1a = N - 1;
                int n1b = qt * 32 + 16 + q4 * 4 + r; if (n1b >= N) n1b = N - 1;
                const short* bpa = bh + n1a * 196;
                const short* bpb = bh + n1b * 196;
                if (kr0 < N) { s00[r] += bf2f(bpa[kr0]); s10[r] += bf2f(bpb[kr0]); }
                if (kr1 < N) { s01[r] += bf2f(bpa[kr1]); s11[r] += bf2f(bpb[kr1]); }
            }
        }
        if (kbase + 32 > N) {
            #pragma unroll
            for (int r = 0; r < 4; ++r) {
                if (kr0 >= N) { s00[r] = -30000.f; s10[r] = -30000.f; }
                if (kr1 >= N) { s01[r] = -30000.f; s11[r] = -30000.f; }
            }
        }

        #pragma unroll
        for (int r = 0; r < 4; ++r) {
            int ra = (q4 * 4 + r) * PSTR, rb = (16 + q4 * 4 + r) * PSTR;
            float e;
            e = __expf(s00[r]); ps0[r] += e; pbuf[ra + c0] = f2bf(e);
            e = __expf(s01[r]); ps0[r] += e; pbuf[ra + c1] = f2bf(e);
            e = __expf(s10[r]); ps1[r] += e; pbuf[rb + c0] = f2bf(e);
            e = __expf(s11[r]); ps1[r] += e; pbuf[rb + c1] = f2bf(e);
        }
        __builtin_amdgcn_wave_barrier();
        short8 ap0 = *(const short8*)(pbuf + r16 * PSTR + rdoff);
        short8 ap1 = *(const short8*)(pbuf + (16 + r16) * PSTR + rdoff);
        short8 bv0 = *(const short8*)(vtile + r16 * PSTR + q4 * 8);
        short8 bv1 = *(const short8*)(vtile + (16 + r16) * PSTR + q4 * 8);
        __builtin_amdgcn_wave_barrier();
        o00 = __builtin_amdgcn_mfma_f32_16x16x32_bf16(ap0, bv0, o00, 0, 0, 0);
        o01 = __builtin_amdgcn_mfma_f32_16x16x32_bf16(ap0, bv1, o01, 0, 0, 0);
        o10 = __builtin_amdgcn_mfma_f32_16x16x32_bf16(ap1, bv0, o10, 0, 0, 0);
        o11 = __builtin_amdgcn_mfma_f32_16x16x32_bf16(ap1, bv1, o11, 0, 0, 0);
    }

    #pragma unroll
    for (int msk = 1; msk < 16; msk <<= 1)
        #pragma unroll
        for (int r = 0; r < 4; ++r) {
            ps0[r] += __shfl_xor(ps0[r], msk);
            ps1[r] += __shfl_xor(ps1[r], msk);
        }

    #pragma unroll
    for (int r = 0; r < 4; ++r) {
        int n1 = qt * 32 + q4 * 4 + r;
        if (n1 < N) {
            float inv = 1.f / fmaxf(ps0[r], 1e-20f);
            size_t row = (size_t)(wbase + n1) * 256;
            aw[row + h * 32 + r16]      = f2bf(o00[r] * inv);
            aw[row + h * 32 + 16 + r16] = f2bf(o01[r] * inv);
        }
        int n2 = qt * 32 + 16 + q4 * 4 + r;
        if (n2 < N) {
            float inv = 1.f / fmaxf(ps1[r], 1e-20f);
            size_t row = (size_t)(wbase + n2) * 256;
            aw[row + h * 32 + r16]      = f2bf(o10[r] * inv);
            aw[row + h * 32 + 16 + r16] = f2bf(o11[r] * inv);
        }
    }
}

__global__ __launch_bounds__(256) void agg_step_kernel(
    const short* __restrict__ xn, const short* __restrict__ pw,
    short* __restrict__ facc, float* __restrict__ mst, float* __restrict__ lst,
    int w0, int N, int branch, int first)
{
    int tp = blockIdx.x * 4 + (threadIdx.x >> 6);
    int lane = threadIdx.x & 63;
    int wl = tp / N, n = tp - wl * N;
    int t = map_t(branch, w0 + wl, n);
    size_t pbase = (size_t)tp * C_DIM + lane * 4;
    size_t tbase = (size_t)t * C_DIM + lane * 4;
    short4v hp = *(const short4v*)(pw + pbase);
    short4v hn = *(const short4v*)(xn + tbase);
    float pv[4], nv[4];
    #pragma unroll
    for (int j = 0; j < 4; ++j) { pv[j] = bf2f(hp[j]); nv[j] = bf2f(hn[j]); }
    float d = pv[0]*nv[0] + pv[1]*nv[1] + pv[2]*nv[2] + pv[3]*nv[3];
    for (int off = 32; off; off >>= 1) d += __shfl_xor(d, off);
    d *= 0.0625f;

    float mo, lo;
    if (first) { mo = -30000.f; lo = 0.f; }
    else       { mo = mst[t];   lo = lst[t]; }
    float mn = fmaxf(mo, d);
    float a  = __expf(mo - mn);
    float e  = __expf(d - mn);
    short4v fo;
    if (first) {
        #pragma unroll
        for (int j = 0; j < 4; ++j) fo[j] = f2bf(e * pv[j]);
    } else {
        short4v hf = *(const short4v*)(facc + tbase);
        #pragma unroll
        for (int j = 0; j < 4; ++j) fo[j] = f2bf(bf2f(hf[j]) * a + e * pv[j]);
    }
    *(short4v*)(facc + tbase) = fo;
    if (lane == 0) { mst[t] = mn; lst[t] = lo * a + e; }
}

__global__ __launch_bounds__(256) void agg_finish_kernel(
    const void* __restrict__ x, short* __restrict__ facc,
    const float* __restrict__ lst, short* __restrict__ xn,
    const short* __restrict__ g2, const short* __restrict__ b2,
    const int* __restrict__ flag)
{
    int t = blockIdx.x * 4 + (threadIdx.x >> 6);
    int lane = threadIdx.x & 63;
    size_t base = (size_t)t * C_DIM + lane * 4;
    float vx[4];
    if (*flag) {
        f32x4 hv = *(const f32x4*)((const float*)x + base);
        #pragma unroll
        for (int j = 0; j < 4; ++j) vx[j] = hv[j];
    } else {
        short4v hv = *(const short4v*)((const short*)x + base);
        #pragma unroll
        for (int j = 0; j < 4; ++j) vx[j] = bf2f(hv[j]);
    }
    short4v hf = *(const short4v*)(facc + base);
    float linv = 1.f / fmaxf(lst[t], 1e-20f);
    float vy[4];
    #pragma unroll
    for (int j = 0; j < 4; ++j) vy[j] = vx[j] + bf2f(hf[j]) * linv;
    float s = 0.f, ss = 0.f;
    #pragma unroll
    for (int j = 0; j < 4; ++j) { s += vy[j]; ss += vy[j] * vy[j]; }
    for (int off = 32; off; off >>= 1) {
        s  += __shfl_xor(s, off);
        ss += __shfl_xor(ss, off);
    }
    float mean = s * (1.f / 256.f);
    float var  = fmaxf(ss * (1.f / 256.f) - mean * mean, 0.f);
    float rstd = rsqrtf(var + 1e-5f);
    short4v hg = *(const short4v*)(g2 + lane * 4);
    short4v hb = *(const short4v*)(b2 + lane * 4);
    short4v oy, on;
    #pragma unroll
    for (int j = 0; j < 4; ++j) {
        oy[j] = f2bf(vy[j]);
        on[j] = f2bf((vy[j] - mean) * rstd * bf2f(hg[j]) + bf2f(hb[j]));
    }
    *(short4v*)(facc + base) = oy;
    *(short4v*)(xn   + base) = on;
}

extern "C" void kernel_launch(void* const* d_in, const int* in_sizes, int n_in,
                              void* d_out, int out_size, void* d_ws, size_t ws_size,
                              hipStream_t stream)
{
    const void* x   = d_in[0];
    const void* g1r = d_in[1];
    const void* b1r = d_in[2];
    const void* g2r = d_in[3];
    const void* b2r = d_in[4];
    const void* wqkv[3]   = {d_in[5], d_in[8],  d_in[11]};
    const void* wproj[3]  = {d_in[6], d_in[9],  d_in[12]};
    const void* bprojr[3] = {d_in[7], d_in[10], d_in[13]};
    const void* rpbr  = d_in[14];
    const void* wfc1  = d_in[15];
    const void* bfc1r = d_in[16];
    const void* wfc2  = d_in[17];
    const void* bfc2r = d_in[18];

    char* ws = (char*)d_ws;
    size_t off = 0;
    auto give = [&](size_t bytes) -> char* {
        char* p = ws + off;
        off += (bytes + 255) & ~(size_t)255;
        return p;
    };
    int*   flag = (int*)give(256);
    short* xn   = (short*)give((size_t)M_TOK * C_DIM * 2);
    short* facc = (short*)give((size_t)M_TOK * C_DIM * 2);
    float* mst  = (float*)give((size_t)M_TOK * 4);
    float* lst  = (float*)give((size_t)M_TOK * 4);
    short* g1 = (short*)give(256 * 2), *b1 = (short*)give(256 * 2);
    short* g2 = (short*)give(256 * 2), *b2 = (short*)give(256 * 2);
    short* bproj[3];
    for (int i = 0; i < 3; ++i) bproj[i] = (short*)give(256 * 2);
    short* bfc1 = (short*)give(1024 * 2), *bfc2 = (short*)give(256 * 2);
    short* bmat = (short*)give((size_t)8 * 196 * 196 * 2);
    short* wqkvT[3], *wprojT[3];
    for (int i = 0; i < 3; ++i) wqkvT[i]  = (short*)give(768 * 256 * 2);
    for (int i = 0; i < 3; ++i) wprojT[i] = (short*)give(256 * 256 * 2);
    short* fc1T = (short*)give(1024 * 256 * 2);
    short* fc2T = (short*)give(256 * 1024 * 2);
    char*  trans = give(26u * 1024 * 1024);

    const float scale = 0.17677669529663687f;   // 1/sqrt(32), folded into Wq

    detect_kernel<<<1, 64, 0, stream>>>((const unsigned*)g1r, flag);
    PrepArgs pa;
    pa.src[0] = g1r;  pa.dst[0] = g1;  pa.n[0] = 256;
    pa.src[1] = b1r;  pa.dst[1] = b1;  pa.n[1] = 256;
    pa.src[2] = g2r;  pa.dst[2] = g2;  pa.n[2] = 256;
    pa.src[3] = b2r;  pa.dst[3] = b2;  pa.n[3] = 256;
    pa.src[4] = bprojr[0]; pa.dst[4] = bproj[0]; pa.n[4] = 256;
    pa.src[5] = bprojr[1]; pa.dst[5] = bproj[1]; pa.n[5] = 256;
    pa.src[6] = bprojr[2]; pa.dst[6] = bproj[2]; pa.n[6] = 256;
    pa.src[7] = bfc1r; pa.dst[7] = bfc1; pa.n[7] = 1024;
    pa.src[8] = bfc2r; pa.dst[8] = bfc2; pa.n[8] = 256;
    prep_kernel<<<12, 256, 0, stream>>>(pa, flag);
    biasmat_kernel<<<(8 * 196 * 196 + 255) / 256, 256, 0, stream>>>(rpbr, bmat, flag);

    TJobs tj;
    tj.smul = scale;
    int pre = 0;
    for (int i = 0; i < 3; ++i) {
        tj.src[i] = wqkv[i]; tj.dst[i] = wqkvT[i];
        tj.R[i] = 256; tj.C[i] = 768; tj.sc[i] = 256; tj.tx[i] = 24;
        tj.pre[i] = pre; pre += 24 * 8;
    }
    for (int i = 0; i < 3; ++i) {
        tj.src[3 + i] = wproj[i]; tj.dst[3 + i] = wprojT[i];
        tj.R[3 + i] = 256; tj.C[3 + i] = 256; tj.sc[3 + i] = 0; tj.tx[3 + i] = 8;
        tj.pre[3 + i] = pre; pre += 8 * 8;
    }
    tj.src[6] = wfc1; tj.dst[6] = fc1T;
    tj.R[6] = 256; tj.C[6] = 1024; tj.sc[6] = 0; tj.tx[6] = 32;
    tj.pre[6] = pre; pre += 32 * 8;
    tj.src[7] = wfc2; tj.dst[7] = fc2T;
    tj.R[7] = 1024; tj.C[7] = 256; tj.sc[7] = 0; tj.tx[7] = 8;
    tj.pre[7] = pre; pre += 8 * 32;
    tj.pre[8] = pre;
    transpose_all_kernel<<<pre, dim3(32, 8), 0, stream>>>(tj, flag);

    ln_kernel<<<M_TOK / 4, 256, 0, stream>>>(x, g1, b1, xn, flag);

    for (int br = 0; br < 3; ++br) {
        const int N      = (br == 2) ? 196 : 784;
        const int NCHUNK = (br == 2) ? 4 : 2;
        const int WPER   = (br == 2) ? 32 : 16;
        const int CHM    = (br == 2) ? 6272 : 12544;
        for (int c = 0; c < NCHUNK; ++c) {
            int t0 = c * CHM;
            int w0 = c * WPER;
            short* qw = (short*)trans;
            short* kw = qw + (size_t)CHM * C_DIM;
            short* vw = kw + (size_t)CHM * C_DIM;
            short* aw = vw + (size_t)CHM * C_DIM;
            dim3 qg(6, CHM / 128);
            if (br == 0)      gemm_qkv128_kernel<0><<<qg, 256, 0, stream>>>(xn + (size_t)t0 * C_DIM, wqkvT[0], qw, kw, vw, t0, w0);
            else if (br == 1) gemm_qkv128_kernel<1><<<qg, 256, 0, stream>>>(xn + (size_t)t0 * C_DIM, wqkvT[1], qw, kw, vw, t0, w0);
            else              gemm_qkv128_kernel<2><<<qg, 256, 0, stream>>>(xn + (size_t)t0 * C_DIM, wqkvT[2], qw, kw, vw, t0, w0);
            int QT = (N + 31) >> 5;
            int tasks = WPER * NH * QT;
            attn_kernel<<<tasks, 64, 0, stream>>>(
                qw, kw, vw, (br == 2) ? bmat : nullptr, aw, N);
            gemm128_kernel<<<dim3(2, CHM / 128), 256, 0, stream>>>(
                aw, wprojT[br], qw, 0, 256, 256, bproj[br], 0, nullptr, nullptr);
            agg_step_kernel<<<CHM / 4, 256, 0, stream>>>(
                xn, qw, facc, mst, lst, w0, N, br, br == 0 ? 1 : 0);
        }
    }

    agg_finish_kernel<<<M_TOK / 4, 256, 0, stream>>>(x, facc, lst, xn, g2, b2, flag);

    // MLP in 2 halves (hbuf = 12544 x 1024 bf16 = 25.7 MB fits trans)
    short* hbuf = (short*)trans;
    for (int hhalf = 0; hhalf < 2; ++hhalf) {
        size_t ro = (size_t)hhalf * 12544;
        gemm128_kernel<<<dim3(8, 98), 256, 0, stream>>>(
            xn + ro * C_DIM, fc1T, hbuf, 0, HID_DIM, 256, bfc1, 1, nullptr, nullptr);
        gemm128_kernel<<<dim3(2, 98), 256, 0, stream>>>(
            hbuf, fc2T, d_out, (int)ro, 256, HID_DIM, bfc2, 0,
            facc + ro * C_DIM, flag);
    }
}